// Round 9
// baseline (319.735 us; speedup 1.0000x reference)
//
#include <hip/hip_runtime.h>
#include <hip/hip_bf16.h>
#include <stdint.h>

// minGRU: proj = x@W_f^T + b_f (bf16 GEMM, fused chunk-summary scan) ->
// chunked linear scan replay -> out = h@W_down^T.  B=4 T=4096 D=1024 E=1536.
// GEMM: 256x256 tile, BK=32, 8 waves, 2-deep LDS ring (64KB -> 2 blocks/CU),
// fence vmcnt(0)+barrier, 2 phases/iter {reads -> raw barrier -> lgkmcnt(0)
// AFTER -> 16 MFMA}, T2 XOR swizzle, operand-swapped epilogue, L2-patch map.
// GEMM1 epilogue additionally computes per-chunk scan summaries (Ac,Vc) by
// re-reading its just-written proj tile through L2 (block-exclusive lines).

typedef __bf16 bf16x8 __attribute__((ext_vector_type(8)));
typedef float  f32x4  __attribute__((ext_vector_type(4)));

__device__ __forceinline__ uint16_t f32_to_bf16(float f) {
  union { float f; uint32_t u; } v; v.f = f;
  uint32_t r = (v.u + 0x7FFFu + ((v.u >> 16) & 1u)) >> 16;  // RNE
  return (uint16_t)r;
}
__device__ __forceinline__ float bf16_to_f32(uint16_t u) {
  union { uint32_t u; float f; } v; v.u = ((uint32_t)u) << 16;
  return v.f;
}

__device__ __forceinline__ void gload_lds16(const uint16_t* g, uint16_t* l) {
  __builtin_amdgcn_global_load_lds(
      (__attribute__((address_space(1))) void*)(g),
      (__attribute__((address_space(3))) void*)(l), 16, 0, 0);
}

// ---- gate math: h_t = a*h_{t-1} + v;  a = 1-sigmoid(kz), v = sigmoid(kz)*g(hx)
__device__ __forceinline__ void gate_val(float kz, float hx, float& a, float& v) {
  float ek = __expf(-fabsf(kz));
  float r  = 1.0f / (1.0f + ek);
  float z  = (kz >= 0.0f) ? r : ek * r;   // sigmoid(k)
  a        = (kz >= 0.0f) ? ek * r : r;   // 1 - sigmoid(k)
  float g;
  if (hx >= 0.0f) {
    g = hx + 0.5f;
  } else {
    float eh = __expf(hx);
    g = eh / (1.0f + eh);
  }
  v = z * g;
}
__device__ __forceinline__ void gate_from_u32(uint32_t u, float& a, float& v) {
  float kz = bf16_to_f32((uint16_t)(u & 0xFFFFu));
  float hx = bf16_to_f32((uint16_t)(u >> 16));
  gate_val(kz, hx, a, v);
}

__device__ __forceinline__ void cast4(const float* s, uint16_t* d, int j) {
  float4 v = reinterpret_cast<const float4*>(s)[j];
  ushort4 o;
  o.x = f32_to_bf16(v.x); o.y = f32_to_bf16(v.y);
  o.z = f32_to_bf16(v.z); o.w = f32_to_bf16(v.w);
  reinterpret_cast<ushort4*>(d)[j] = o;
}

// ---- fused cast: x, W_f (row-interleaved), W_down, bias (permuted) ----
__global__ __launch_bounds__(256) void cast_all(
    const float* __restrict__ x,   uint16_t* __restrict__ x_bf,
    const float* __restrict__ W_f, uint16_t* __restrict__ Wf_bf,
    const float* __restrict__ b_f, float* __restrict__ bias_p,
    const float* __restrict__ W_d, uint16_t* __restrict__ Wd_bf) {
  const int stride = gridDim.x * blockDim.x;
  const int gid = blockIdx.x * blockDim.x + threadIdx.x;
  if (gid < 3072)  // bias permute: col 2e <- b_f[e], col 2e+1 <- b_f[1536+e]
    bias_p[gid] = b_f[(gid & 1) ? 1536 + (gid >> 1) : (gid >> 1)];
  for (int i = gid; i < 4194304; i += stride) cast4(x, x_bf, i);
  for (int i = gid; i < 786432; i += stride) {
    const int r = i >> 8, cg = i & 255;
    const int rp = (r < 1536) ? (r << 1) : (((r - 1536) << 1) | 1);
    float4 v = reinterpret_cast<const float4*>(W_f)[i];
    ushort4 o;
    o.x = f32_to_bf16(v.x); o.y = f32_to_bf16(v.y);
    o.z = f32_to_bf16(v.z); o.w = f32_to_bf16(v.w);
    reinterpret_cast<ushort4*>(Wf_bf)[rp * 256 + cg] = o;
  }
  for (int i = gid; i < 393216; i += stride) cast4(W_d, Wd_bf, i);
}

// ---------------- bf16 GEMM, C = A(M,K) * Bt(N,K)^T, 256^2, ring-2 ----------
// Requires M == 16384 (64 m-tiles), N % 1024 == 0.
// Ring: 2 bufs x 32KB (64KB -> 2 blocks/CU at VGPR 96). Iter u reads buf[u&1],
// stages tile u+1 into buf[(u+1)&1] (disjoint). Fence: vmcnt(0)+barrier.
// WAR: at fence u, every wave drained its buf[(u+1)&1] (tile u-1) reads via its
// per-phase lgkmcnt(0) -> overwrite safe. RAW: vmcnt(0) => tile u landed.
// FUSE_SCAN: epilogue computes per-chunk (A,V) summaries from the just-written
// proj tile (re-read via L2; lines are block-exclusive and never L1-cached).
template <int OUT_BF16_BIAS, int FUSE_SCAN>
__global__ __launch_bounds__(512, 2) void gemm256(
    const uint16_t* __restrict__ A, const uint16_t* __restrict__ Bt,
    const float* __restrict__ bias, void* __restrict__ Cout,
    float* __restrict__ Ac, float* __restrict__ Vc,
    int M, int N, int K) {
  __shared__ alignas(16) uint16_t lds[2 * 16384];  // 64 KB

  const int tid  = threadIdx.x;
  const int wave = tid >> 6;
  const int lane = tid & 63;
  const int wr = wave >> 2;
  const int wc = wave & 3;

  // L2-fitting patch map (2m x 4n tiles per patch; XCD x = bid&7)
  const int bid = (int)blockIdx.x;
  const int xq  = bid & 7;
  const int j   = bid >> 3;
  const int pi  = xq + ((j >> 3) << 3);
  const int q   = j & 7;
  const int mt  = ((pi & 31) << 1) + (q >> 2);
  const int nt  = ((pi >> 5) << 2) + (q & 3);
  const int m0  = mt << 8;
  const int n0  = nt << 8;

  const int NT = K >> 5;  // BK = 32

  const int srow = wave * 16 + (lane >> 2);
  const int skg  = (lane & 3) ^ ((lane >> 3) & 3);
  const uint16_t* Ag0 = A  + (size_t)(m0 + srow) * K + skg * 8;
  const uint16_t* Ag1 = A  + (size_t)(m0 + 128 + srow) * K + skg * 8;
  const uint16_t* Bg0 = Bt + (size_t)(n0 + srow) * K + skg * 8;
  const uint16_t* Bg1 = Bt + (size_t)(n0 + 128 + srow) * K + skg * 8;
  const int sdw = wave * 512;

  const int kgq = (lane >> 4) ^ ((lane >> 1) & 3);
  const int rA = (wr * 128 + (lane & 15)) * 32 + kgq * 8;
  const int rB = (wc * 64  + (lane & 15)) * 32 + kgq * 8;

  f32x4 acc[8][4] = {};

  // prologue: stage tile 0
  gload_lds16(Ag0, &lds[sdw]);
  gload_lds16(Ag1, &lds[4096 + sdw]);
  gload_lds16(Bg0, &lds[8192 + sdw]);
  gload_lds16(Bg1, &lds[12288 + sdw]);

  for (int u = 0; u < NT; ++u) {
    const uint16_t* Ab = &lds[(u & 1) * 16384 + rA];
    const uint16_t* Bb = &lds[(u & 1) * 16384 + 8192 + rB];
    const int us = (u + 1 < NT) ? (u + 1) : (NT - 1);  // clamp: uniform vmcnt
    uint16_t* sb = &lds[((u + 1) & 1) * 16384];
    const size_t kofs = (size_t)us * 32;

    // fence: tile u landed; all waves consumed tile u-1 (per-phase lgkmcnt(0))
    asm volatile("s_waitcnt vmcnt(0)" ::: "memory");
    __builtin_amdgcn_s_barrier();

    bf16x8 af0[4], af1[4], bfr[4];
    // ---- ph0: reads + A-stage; barrier; drain AFTER barrier ----
#pragma unroll
    for (int m = 0; m < 4; ++m) af0[m] = *reinterpret_cast<const bf16x8*>(Ab + m * 512);
#pragma unroll
    for (int n = 0; n < 4; ++n) bfr[n] = *reinterpret_cast<const bf16x8*>(Bb + n * 512);
    gload_lds16(Ag0 + kofs, sb + sdw);
    gload_lds16(Ag1 + kofs, sb + 4096 + sdw);
    __builtin_amdgcn_sched_barrier(0);
    __builtin_amdgcn_s_barrier();
    asm volatile("s_waitcnt lgkmcnt(0)" ::: "memory");
    __builtin_amdgcn_sched_barrier(0);
    __builtin_amdgcn_s_setprio(1);
#pragma unroll
    for (int m = 0; m < 4; ++m)
#pragma unroll
      for (int n = 0; n < 4; ++n)
        acc[m][n] = __builtin_amdgcn_mfma_f32_16x16x32_bf16(bfr[n], af0[m], acc[m][n], 0, 0, 0);
    __builtin_amdgcn_s_setprio(0);
    __builtin_amdgcn_sched_barrier(0);

    // ---- ph1: A4-7 reads + B-stage ----
#pragma unroll
    for (int m = 0; m < 4; ++m) af1[m] = *reinterpret_cast<const bf16x8*>(Ab + (m + 4) * 512);
    gload_lds16(Bg0 + kofs, sb + 8192 + sdw);
    gload_lds16(Bg1 + kofs, sb + 12288 + sdw);
    __builtin_amdgcn_sched_barrier(0);
    __builtin_amdgcn_s_barrier();
    asm volatile("s_waitcnt lgkmcnt(0)" ::: "memory");
    __builtin_amdgcn_sched_barrier(0);
    __builtin_amdgcn_s_setprio(1);
#pragma unroll
    for (int m = 0; m < 4; ++m)
#pragma unroll
      for (int n = 0; n < 4; ++n)
        acc[m + 4][n] = __builtin_amdgcn_mfma_f32_16x16x32_bf16(bfr[n], af1[m], acc[m + 4][n], 0, 0, 0);
    __builtin_amdgcn_s_setprio(0);
    __builtin_amdgcn_sched_barrier(0);
  }
  asm volatile("s_waitcnt vmcnt(0)" ::: "memory");

  // ---- epilogue (operand-swapped layout):
  //   row = m0 + wr*128 + m*16 + (lane&15)
  //   col = n0 + wc*64 + n*16 + (lane>>4)*4 + i
  const int r0 = m0 + wr * 128 + (lane & 15);
  const int cb = n0 + wc * 64 + (lane >> 4) * 4;
  if constexpr (OUT_BF16_BIAS) {
    uint16_t* C = (uint16_t*)Cout;
#pragma unroll
    for (int m = 0; m < 8; ++m) {
      const int row = r0 + m * 16;
#pragma unroll
      for (int n = 0; n < 4; ++n) {
        const int col = cb + n * 16;
        ushort4 o;
        o.x = f32_to_bf16(acc[m][n][0] + bias[col + 0]);
        o.y = f32_to_bf16(acc[m][n][1] + bias[col + 1]);
        o.z = f32_to_bf16(acc[m][n][2] + bias[col + 2]);
        o.w = f32_to_bf16(acc[m][n][3] + bias[col + 3]);
        *reinterpret_cast<ushort4*>(&C[(size_t)row * N + col]) = o;
      }
    }
  } else {
    float* C = (float*)Cout;
#pragma unroll
    for (int m = 0; m < 8; ++m) {
      const int row = r0 + m * 16;
#pragma unroll
      for (int n = 0; n < 4; ++n) {
        const int col = cb + n * 16;
        float4 o;
        o.x = acc[m][n][0]; o.y = acc[m][n][1];
        o.z = acc[m][n][2]; o.w = acc[m][n][3];
        *reinterpret_cast<float4*>(&C[(size_t)row * N + col]) = o;
      }
    }
  }

  if constexpr (FUSE_SCAN) {
    // All proj stores visible in L2 before any re-read (vmcnt counts stores).
    asm volatile("s_waitcnt vmcnt(0)" ::: "memory");
    __builtin_amdgcn_s_barrier();
    // 512 threads -> 4 chunks x 128 e-channels of this block's tile.
    const int cidx = tid >> 7;            // 0..3
    const int el   = tid & 127;
    const int b    = m0 >> 12;            // batch (T = 4096)
    const int c    = ((m0 & 4095) >> 6) + cidx;   // global chunk (L = 64)
    const uint16_t* pr = (const uint16_t*)Cout +
        (size_t)(m0 + cidx * 64) * N + n0 + 2 * el;
    float Aa = 1.0f, Vv = 0.0f;
#pragma unroll 8
    for (int t = 0; t < 64; ++t) {
      uint32_t u32 = *reinterpret_cast<const uint32_t*>(pr);
      float a, v; gate_from_u32(u32, a, v);
      Aa *= a;
      Vv = a * Vv + v;
      pr += N;
    }
    const int E = N >> 1;
    const size_t idx = ((size_t)(b * 64 + c)) * E + (n0 >> 1) + el;
    Ac[idx] = Aa; Vc[idx] = Vv;
  }
}

// pass3: replay chunks with true h_start (scans predecessor summaries first).
__global__ __launch_bounds__(256) void scan_pass3(
    const uint16_t* __restrict__ proj, const float* __restrict__ Ac,
    const float* __restrict__ Vc, uint16_t* __restrict__ hout,
    int T, int E, int CH, int L) {
  const int e = blockIdx.x * 256 + threadIdx.x;
  const int c = blockIdx.y;
  const int b = blockIdx.z;
  const int N1 = 2 * E;
  float h = 0.5f;  // h_0 = g(0)
  for (int cc = 0; cc < c; ++cc) {
    const size_t idx = ((size_t)(b * CH + cc)) * E + e;
    h = Ac[idx] * h + Vc[idx];
  }
  const uint16_t* p = proj + (size_t)(b * T + c * L) * N1 + 2 * e;
  uint16_t* o = hout + (size_t)(b * T + c * L) * E + e;
#pragma unroll 4
  for (int t = 0; t < L; ++t) {
    float a, v; gate_from_u32(*reinterpret_cast<const uint32_t*>(p), a, v);
    h = a * h + v;
    *o = f32_to_bf16(h);
    p += N1; o += E;
  }
}

extern "C" void kernel_launch(void* const* d_in, const int* in_sizes, int n_in,
                              void* d_out, int out_size, void* d_ws, size_t ws_size,
                              hipStream_t stream) {
  const float* x   = (const float*)d_in[0];
  const float* W_f = (const float*)d_in[1];
  const float* b_f = (const float*)d_in[2];
  const float* W_d = (const float*)d_in[3];
  const int Bb = 4, T = 4096, D = 1024, E = 1536;
  const int M = Bb * T;        // 16384
  const int N1 = 2 * E;        // 3072
  const int CH = 64, L = T / CH;

  char* w = (char*)d_ws;
  uint16_t* x_bf  = (uint16_t*)w; w += (size_t)M * D * 2;
  uint16_t* Wf_bf = (uint16_t*)w; w += (size_t)N1 * D * 2;
  uint16_t* Wd_bf = (uint16_t*)w; w += (size_t)D * E * 2;
  uint16_t* proj  = (uint16_t*)w; w += (size_t)M * N1 * 2;
  uint16_t* h_bf  = (uint16_t*)w; w += (size_t)M * E * 2;
  float* Ac     = (float*)w; w += (size_t)Bb * CH * E * 4;
  float* Vc     = (float*)w; w += (size_t)Bb * CH * E * 4;
  float* bias_p = (float*)w; w += (size_t)N1 * 4;

  cast_all<<<2048, 256, 0, stream>>>(x, x_bf, W_f, Wf_bf, b_f, bias_p, W_d, Wd_bf);

  // proj = x @ Wf_perm^T + bias_p (bf16, interleaved cols) + chunk summaries
  gemm256<1, 1><<<(M / 256) * (N1 / 256), 512, 0, stream>>>(
      x_bf, Wf_bf, bias_p, proj, Ac, Vc, M, N1, D);

  scan_pass3<<<dim3(E / 256, CH, Bb), 256, 0, stream>>>(proj, Ac, Vc, h_bf, T, E, CH, L);

  // out = h @ W_down^T (fp32 out)
  gemm256<0, 0><<<(M / 256) * (D / 256), 512, 0, stream>>>(
      h_bf, Wd_bf, nullptr, d_out, nullptr, nullptr, M, D, E);
}

// Round 10
// 317.040 us; speedup vs baseline: 1.0085x; 1.0085x over previous
//
#include <hip/hip_runtime.h>
#include <hip/hip_bf16.h>
#include <stdint.h>

// minGRU: proj = x@W_f^T + b_f (bf16 GEMM, fused chunk-summary scan in epilogue)
// -> chunked scan replay -> out = h@W_down^T.  B=4 T=4096 D=1024 E=1536.
// GEMM (R6/R8-verified): 256x256, BK=32, 8 waves, 4-deep LDS ring, vmcnt(8),
// 2 phases/iter {reads -> raw barrier -> lgkmcnt(0) AFTER -> 16 MFMA},
// T2 XOR swizzle, operand-swapped epilogue, L2-patch map.

typedef __bf16 bf16x8 __attribute__((ext_vector_type(8)));
typedef float  f32x4  __attribute__((ext_vector_type(4)));

__device__ __forceinline__ uint16_t f32_to_bf16(float f) {
  union { float f; uint32_t u; } v; v.f = f;
  uint32_t r = (v.u + 0x7FFFu + ((v.u >> 16) & 1u)) >> 16;  // RNE
  return (uint16_t)r;
}
__device__ __forceinline__ float bf16_to_f32(uint16_t u) {
  union { uint32_t u; float f; } v; v.u = ((uint32_t)u) << 16;
  return v.f;
}

__device__ __forceinline__ void gload_lds16(const uint16_t* g, uint16_t* l) {
  __builtin_amdgcn_global_load_lds(
      (__attribute__((address_space(1))) void*)(g),
      (__attribute__((address_space(3))) void*)(l), 16, 0, 0);
}

// ---- gate math: h_t = a*h_{t-1} + v;  a = 1-sigmoid(kz), v = sigmoid(kz)*g(hx)
__device__ __forceinline__ void gate_val(float kz, float hx, float& a, float& v) {
  float ek = __expf(-fabsf(kz));
  float r  = 1.0f / (1.0f + ek);
  float z  = (kz >= 0.0f) ? r : ek * r;   // sigmoid(k)
  a        = (kz >= 0.0f) ? ek * r : r;   // 1 - sigmoid(k)
  float g;
  if (hx >= 0.0f) {
    g = hx + 0.5f;
  } else {
    float eh = __expf(hx);
    g = eh / (1.0f + eh);
  }
  v = z * g;
}
__device__ __forceinline__ void gate_from_u32(uint32_t u, float& a, float& v) {
  float kz = bf16_to_f32((uint16_t)(u & 0xFFFFu));
  float hx = bf16_to_f32((uint16_t)(u >> 16));
  gate_val(kz, hx, a, v);
}

__device__ __forceinline__ void cast4(const float* s, uint16_t* d, int j) {
  float4 v = reinterpret_cast<const float4*>(s)[j];
  ushort4 o;
  o.x = f32_to_bf16(v.x); o.y = f32_to_bf16(v.y);
  o.z = f32_to_bf16(v.z); o.w = f32_to_bf16(v.w);
  reinterpret_cast<ushort4*>(d)[j] = o;
}

// ---- fused cast: x, W_f (row-interleaved), W_down, bias (permuted) ----
__global__ __launch_bounds__(256) void cast_all(
    const float* __restrict__ x,   uint16_t* __restrict__ x_bf,
    const float* __restrict__ W_f, uint16_t* __restrict__ Wf_bf,
    const float* __restrict__ b_f, float* __restrict__ bias_p,
    const float* __restrict__ W_d, uint16_t* __restrict__ Wd_bf) {
  const int stride = gridDim.x * blockDim.x;
  const int gid = blockIdx.x * blockDim.x + threadIdx.x;
  if (gid < 3072)  // bias permute: col 2e <- b_f[e], col 2e+1 <- b_f[1536+e]
    bias_p[gid] = b_f[(gid & 1) ? 1536 + (gid >> 1) : (gid >> 1)];
  for (int i = gid; i < 4194304; i += stride) cast4(x, x_bf, i);
  for (int i = gid; i < 786432; i += stride) {
    const int r = i >> 8, cg = i & 255;
    const int rp = (r < 1536) ? (r << 1) : (((r - 1536) << 1) | 1);
    float4 v = reinterpret_cast<const float4*>(W_f)[i];
    ushort4 o;
    o.x = f32_to_bf16(v.x); o.y = f32_to_bf16(v.y);
    o.z = f32_to_bf16(v.z); o.w = f32_to_bf16(v.w);
    reinterpret_cast<ushort4*>(Wf_bf)[rp * 256 + cg] = o;
  }
  for (int i = gid; i < 393216; i += stride) cast4(W_d, Wd_bf, i);
}

// ---------------- bf16 GEMM, C = A(M,K) * Bt(N,K)^T, 256^2, ring-4 ----------
// (R6/R8-verified loop, byte-for-byte.)  FUSE_SCAN adds an epilogue phase that
// computes per-chunk scan summaries (Ac,Vc) from the just-written proj tile
// (block-exclusive lines, re-read via L2 after vmcnt(0)+barrier).
template <int OUT_BF16_BIAS, int FUSE_SCAN>
__global__ __launch_bounds__(512, 2) void gemm256(
    const uint16_t* __restrict__ A, const uint16_t* __restrict__ Bt,
    const float* __restrict__ bias, void* __restrict__ Cout,
    float* __restrict__ Ac, float* __restrict__ Vc,
    int M, int N, int K) {
  __shared__ alignas(16) uint16_t lds[4 * 16384];  // 128 KB

  const int tid  = threadIdx.x;
  const int wave = tid >> 6;
  const int lane = tid & 63;
  const int wr = wave >> 2;
  const int wc = wave & 3;

  // L2-fitting patch map (2m x 4n tiles per patch; XCD x = bid&7)
  const int bid = (int)blockIdx.x;
  const int xq  = bid & 7;
  const int j   = bid >> 3;
  const int pi  = xq + ((j >> 3) << 3);
  const int q   = j & 7;
  const int mt  = ((pi & 31) << 1) + (q >> 2);
  const int nt  = ((pi >> 5) << 2) + (q & 3);
  const int m0  = mt << 8;
  const int n0  = nt << 8;

  const int NT = K >> 5;  // BK = 32

  const int srow = wave * 16 + (lane >> 2);
  const int skg  = (lane & 3) ^ ((lane >> 3) & 3);
  const uint16_t* Ag0 = A  + (size_t)(m0 + srow) * K + skg * 8;
  const uint16_t* Ag1 = A  + (size_t)(m0 + 128 + srow) * K + skg * 8;
  const uint16_t* Bg0 = Bt + (size_t)(n0 + srow) * K + skg * 8;
  const uint16_t* Bg1 = Bt + (size_t)(n0 + 128 + srow) * K + skg * 8;
  const int sdw = wave * 512;

  const int kgq = (lane >> 4) ^ ((lane >> 1) & 3);
  const int rA = (wr * 128 + (lane & 15)) * 32 + kgq * 8;
  const int rB = (wc * 64  + (lane & 15)) * 32 + kgq * 8;

  f32x4 acc[8][4] = {};

#pragma unroll
  for (int tt = 0; tt < 3; ++tt) {
    uint16_t* sb = &lds[tt * 16384];
    gload_lds16(Ag0 + tt * 32, sb + sdw);
    gload_lds16(Ag1 + tt * 32, sb + 4096 + sdw);
    gload_lds16(Bg0 + tt * 32, sb + 8192 + sdw);
    gload_lds16(Bg1 + tt * 32, sb + 12288 + sdw);
  }

  for (int u = 0; u < NT; ++u) {
    const uint16_t* Ab = &lds[(u & 3) * 16384 + rA];
    const uint16_t* Bb = &lds[(u & 3) * 16384 + 8192 + rB];
    const int us = (u + 3 < NT) ? (u + 3) : (NT - 1);
    uint16_t* sb = &lds[((u + 3) & 3) * 16384];
    const size_t kofs = (size_t)us * 32;

    asm volatile("s_waitcnt vmcnt(8)" ::: "memory");
    __builtin_amdgcn_s_barrier();

    bf16x8 af0[4], af1[4], bfr[4];
#pragma unroll
    for (int m = 0; m < 4; ++m) af0[m] = *reinterpret_cast<const bf16x8*>(Ab + m * 512);
#pragma unroll
    for (int n = 0; n < 4; ++n) bfr[n] = *reinterpret_cast<const bf16x8*>(Bb + n * 512);
    gload_lds16(Ag0 + kofs, sb + sdw);
    gload_lds16(Ag1 + kofs, sb + 4096 + sdw);
    __builtin_amdgcn_sched_barrier(0);
    __builtin_amdgcn_s_barrier();
    asm volatile("s_waitcnt lgkmcnt(0)" ::: "memory");
    __builtin_amdgcn_sched_barrier(0);
    __builtin_amdgcn_s_setprio(1);
#pragma unroll
    for (int m = 0; m < 4; ++m)
#pragma unroll
      for (int n = 0; n < 4; ++n)
        acc[m][n] = __builtin_amdgcn_mfma_f32_16x16x32_bf16(bfr[n], af0[m], acc[m][n], 0, 0, 0);
    __builtin_amdgcn_s_setprio(0);
    __builtin_amdgcn_sched_barrier(0);

#pragma unroll
    for (int m = 0; m < 4; ++m) af1[m] = *reinterpret_cast<const bf16x8*>(Ab + (m + 4) * 512);
    gload_lds16(Bg0 + kofs, sb + 8192 + sdw);
    gload_lds16(Bg1 + kofs, sb + 12288 + sdw);
    __builtin_amdgcn_sched_barrier(0);
    __builtin_amdgcn_s_barrier();
    asm volatile("s_waitcnt lgkmcnt(0)" ::: "memory");
    __builtin_amdgcn_sched_barrier(0);
    __builtin_amdgcn_s_setprio(1);
#pragma unroll
    for (int m = 0; m < 4; ++m)
#pragma unroll
      for (int n = 0; n < 4; ++n)
        acc[m + 4][n] = __builtin_amdgcn_mfma_f32_16x16x32_bf16(bfr[n], af1[m], acc[m + 4][n], 0, 0, 0);
    __builtin_amdgcn_s_setprio(0);
    __builtin_amdgcn_sched_barrier(0);
  }
  asm volatile("s_waitcnt vmcnt(0)" ::: "memory");

  // ---- epilogue (operand-swapped layout):
  //   row = m0 + wr*128 + m*16 + (lane&15)
  //   col = n0 + wc*64 + n*16 + (lane>>4)*4 + i
  const int r0 = m0 + wr * 128 + (lane & 15);
  const int cb = n0 + wc * 64 + (lane >> 4) * 4;
  if constexpr (OUT_BF16_BIAS) {
    uint16_t* C = (uint16_t*)Cout;
#pragma unroll
    for (int m = 0; m < 8; ++m) {
      const int row = r0 + m * 16;
#pragma unroll
      for (int n = 0; n < 4; ++n) {
        const int col = cb + n * 16;
        ushort4 o;
        o.x = f32_to_bf16(acc[m][n][0] + bias[col + 0]);
        o.y = f32_to_bf16(acc[m][n][1] + bias[col + 1]);
        o.z = f32_to_bf16(acc[m][n][2] + bias[col + 2]);
        o.w = f32_to_bf16(acc[m][n][3] + bias[col + 3]);
        *reinterpret_cast<ushort4*>(&C[(size_t)row * N + col]) = o;
      }
    }
  } else {
    float* C = (float*)Cout;
#pragma unroll
    for (int m = 0; m < 8; ++m) {
      const int row = r0 + m * 16;
#pragma unroll
      for (int n = 0; n < 4; ++n) {
        const int col = cb + n * 16;
        float4 o;
        o.x = acc[m][n][0]; o.y = acc[m][n][1];
        o.z = acc[m][n][2]; o.w = acc[m][n][3];
        *reinterpret_cast<float4*>(&C[(size_t)row * N + col]) = o;
      }
    }
  }

  if constexpr (FUSE_SCAN) {
    // This block's proj tile (rows m0..m0+255, cols n0..n0+255) is exclusive.
    // vmcnt(0) drains each wave's stores; barrier -> all waves' stores in L2.
    asm volatile("s_waitcnt vmcnt(0)" ::: "memory");
    __builtin_amdgcn_s_barrier();
    // 512 threads -> 4 chunks (L=64 rows) x 128 e-channels.
    const int cidx = tid >> 7;                   // 0..3
    const int el   = tid & 127;
    const int b    = m0 >> 12;                   // batch (T = 4096)
    const int c    = ((m0 & 4095) >> 6) + cidx;  // global chunk id
    const uint16_t* pr = (const uint16_t*)Cout +
        (size_t)(m0 + cidx * 64) * N + n0 + 2 * el;
    float Aa = 1.0f, Vv = 0.0f;
#pragma unroll 8
    for (int t = 0; t < 64; ++t) {
      uint32_t u32 = *reinterpret_cast<const uint32_t*>(pr);
      float a, v; gate_from_u32(u32, a, v);
      Aa *= a;
      Vv = a * Vv + v;
      pr += N;
    }
    const int E = N >> 1;
    const size_t idx = ((size_t)(b * 64 + c)) * E + (n0 >> 1) + el;
    Ac[idx] = Aa; Vc[idx] = Vv;
  }
}

// pass3: replay chunks with true h_start (scans predecessor summaries first).
__global__ __launch_bounds__(256) void scan_pass3(
    const uint16_t* __restrict__ proj, const float* __restrict__ Ac,
    const float* __restrict__ Vc, uint16_t* __restrict__ hout,
    int T, int E, int CH, int L) {
  const int e = blockIdx.x * 256 + threadIdx.x;
  const int c = blockIdx.y;
  const int b = blockIdx.z;
  const int N1 = 2 * E;
  float h = 0.5f;  // h_0 = g(0)
  for (int cc = 0; cc < c; ++cc) {
    const size_t idx = ((size_t)(b * CH + cc)) * E + e;
    h = Ac[idx] * h + Vc[idx];
  }
  const uint16_t* p = proj + (size_t)(b * T + c * L) * N1 + 2 * e;
  uint16_t* o = hout + (size_t)(b * T + c * L) * E + e;
#pragma unroll 4
  for (int t = 0; t < L; ++t) {
    float a, v; gate_from_u32(*reinterpret_cast<const uint32_t*>(p), a, v);
    h = a * h + v;
    *o = f32_to_bf16(h);
    p += N1; o += E;
  }
}

extern "C" void kernel_launch(void* const* d_in, const int* in_sizes, int n_in,
                              void* d_out, int out_size, void* d_ws, size_t ws_size,
                              hipStream_t stream) {
  const float* x   = (const float*)d_in[0];
  const float* W_f = (const float*)d_in[1];
  const float* b_f = (const float*)d_in[2];
  const float* W_d = (const float*)d_in[3];
  const int Bb = 4, T = 4096, D = 1024, E = 1536;
  const int M = Bb * T;        // 16384
  const int N1 = 2 * E;        // 3072
  const int CH = 64, L = T / CH;

  char* w = (char*)d_ws;
  uint16_t* x_bf  = (uint16_t*)w; w += (size_t)M * D * 2;
  uint16_t* Wf_bf = (uint16_t*)w; w += (size_t)N1 * D * 2;
  uint16_t* Wd_bf = (uint16_t*)w; w += (size_t)D * E * 2;
  uint16_t* proj  = (uint16_t*)w; w += (size_t)M * N1 * 2;
  uint16_t* h_bf  = (uint16_t*)w; w += (size_t)M * E * 2;
  float* Ac     = (float*)w; w += (size_t)Bb * CH * E * 4;
  float* Vc     = (float*)w; w += (size_t)Bb * CH * E * 4;
  float* bias_p = (float*)w; w += (size_t)N1 * 4;

  cast_all<<<2048, 256, 0, stream>>>(x, x_bf, W_f, Wf_bf, b_f, bias_p, W_d, Wd_bf);

  // proj = x @ Wf_perm^T + bias_p (bf16, interleaved cols) + chunk summaries
  gemm256<1, 1><<<(M / 256) * (N1 / 256), 512, 0, stream>>>(
      x_bf, Wf_bf, bias_p, proj, Ac, Vc, M, N1, D);

  scan_pass3<<<dim3(E / 256, CH, Bb), 256, 0, stream>>>(proj, Ac, Vc, h_bf, T, E, CH, L);

  // out = h @ W_down^T (fp32 out)
  gemm256<0, 0><<<(M / 256) * (D / 256), 512, 0, stream>>>(
      h_bf, Wd_bf, nullptr, d_out, nullptr, nullptr, M, D, E);
}

// Round 11
// 289.233 us; speedup vs baseline: 1.1055x; 1.0961x over previous
//
#include <hip/hip_runtime.h>
#include <hip/hip_bf16.h>
#include <stdint.h>

// minGRU: proj = x@W_f^T + b_f (bf16 GEMM; chunk-summary scan fused IN-REGISTER
// in epilogue) -> chunked scan replay -> out = h@W_down^T. B=4 T=4096 D=1024 E=1536.
// GEMM (R6/R8-verified): 256x256, BK=32, 8 waves, 4-deep LDS ring, vmcnt(8),
// 2 phases/iter {reads -> raw barrier -> lgkmcnt(0) AFTER -> 16 MFMA},
// T2 XOR swizzle, operand-swapped epilogue, L2-patch map.
// R11: summaries from acc registers via 16-lane affine shuffle-scan (no re-read;
// R10's global re-read hit L2 eviction by concurrent streaming blocks).

typedef __bf16 bf16x8 __attribute__((ext_vector_type(8)));
typedef float  f32x4  __attribute__((ext_vector_type(4)));

__device__ __forceinline__ uint16_t f32_to_bf16(float f) {
  union { float f; uint32_t u; } v; v.f = f;
  uint32_t r = (v.u + 0x7FFFu + ((v.u >> 16) & 1u)) >> 16;  // RNE
  return (uint16_t)r;
}
__device__ __forceinline__ float bf16_to_f32(uint16_t u) {
  union { uint32_t u; float f; } v; v.u = ((uint32_t)u) << 16;
  return v.f;
}
__device__ __forceinline__ float bf16r(float f) {  // round f to bf16 grid
  return bf16_to_f32(f32_to_bf16(f));
}

__device__ __forceinline__ void gload_lds16(const uint16_t* g, uint16_t* l) {
  __builtin_amdgcn_global_load_lds(
      (__attribute__((address_space(1))) void*)(g),
      (__attribute__((address_space(3))) void*)(l), 16, 0, 0);
}

// ---- gate math: h_t = a*h_{t-1} + v;  a = 1-sigmoid(kz), v = sigmoid(kz)*g(hx)
__device__ __forceinline__ void gate_val(float kz, float hx, float& a, float& v) {
  float ek = __expf(-fabsf(kz));
  float r  = 1.0f / (1.0f + ek);
  float z  = (kz >= 0.0f) ? r : ek * r;   // sigmoid(k)
  a        = (kz >= 0.0f) ? ek * r : r;   // 1 - sigmoid(k)
  float g;
  if (hx >= 0.0f) {
    g = hx + 0.5f;
  } else {
    float eh = __expf(hx);
    g = eh / (1.0f + eh);
  }
  v = z * g;
}
__device__ __forceinline__ void gate_from_u32(uint32_t u, float& a, float& v) {
  float kz = bf16_to_f32((uint16_t)(u & 0xFFFFu));
  float hx = bf16_to_f32((uint16_t)(u >> 16));
  gate_val(kz, hx, a, v);
}

__device__ __forceinline__ void cast4(const float* s, uint16_t* d, int j) {
  float4 v = reinterpret_cast<const float4*>(s)[j];
  ushort4 o;
  o.x = f32_to_bf16(v.x); o.y = f32_to_bf16(v.y);
  o.z = f32_to_bf16(v.z); o.w = f32_to_bf16(v.w);
  reinterpret_cast<ushort4*>(d)[j] = o;
}

// ---- fused cast: x, W_f (row-interleaved), W_down, bias (permuted) ----
__global__ __launch_bounds__(256) void cast_all(
    const float* __restrict__ x,   uint16_t* __restrict__ x_bf,
    const float* __restrict__ W_f, uint16_t* __restrict__ Wf_bf,
    const float* __restrict__ b_f, float* __restrict__ bias_p,
    const float* __restrict__ W_d, uint16_t* __restrict__ Wd_bf) {
  const int stride = gridDim.x * blockDim.x;
  const int gid = blockIdx.x * blockDim.x + threadIdx.x;
  if (gid < 3072)  // bias permute: col 2e <- b_f[e], col 2e+1 <- b_f[1536+e]
    bias_p[gid] = b_f[(gid & 1) ? 1536 + (gid >> 1) : (gid >> 1)];
  for (int i = gid; i < 4194304; i += stride) cast4(x, x_bf, i);
  for (int i = gid; i < 786432; i += stride) {
    const int r = i >> 8, cg = i & 255;
    const int rp = (r < 1536) ? (r << 1) : (((r - 1536) << 1) | 1);
    float4 v = reinterpret_cast<const float4*>(W_f)[i];
    ushort4 o;
    o.x = f32_to_bf16(v.x); o.y = f32_to_bf16(v.y);
    o.z = f32_to_bf16(v.z); o.w = f32_to_bf16(v.w);
    reinterpret_cast<ushort4*>(Wf_bf)[rp * 256 + cg] = o;
  }
  for (int i = gid; i < 393216; i += stride) cast4(W_d, Wd_bf, i);
}

// ---------------- bf16 GEMM, C = A(M,K) * Bt(N,K)^T, 256^2, ring-4 ----------
// (R6/R8-verified loop.)  FUSE_SCAN: epilogue computes per-chunk scan
// summaries (Ac,Vc) from acc registers via 16-lane affine shuffle-scan.
template <int OUT_BF16_BIAS, int FUSE_SCAN>
__global__ __launch_bounds__(512, 2) void gemm256(
    const uint16_t* __restrict__ A, const uint16_t* __restrict__ Bt,
    const float* __restrict__ bias, void* __restrict__ Cout,
    float* __restrict__ Ac, float* __restrict__ Vc,
    int M, int N, int K) {
  __shared__ alignas(16) uint16_t lds[4 * 16384];  // 128 KB

  const int tid  = threadIdx.x;
  const int wave = tid >> 6;
  const int lane = tid & 63;
  const int wr = wave >> 2;
  const int wc = wave & 3;

  // L2-fitting patch map (2m x 4n tiles per patch; XCD x = bid&7)
  const int bid = (int)blockIdx.x;
  const int xq  = bid & 7;
  const int j   = bid >> 3;
  const int pi  = xq + ((j >> 3) << 3);
  const int q   = j & 7;
  const int mt  = ((pi & 31) << 1) + (q >> 2);
  const int nt  = ((pi >> 5) << 2) + (q & 3);
  const int m0  = mt << 8;
  const int n0  = nt << 8;

  const int NT = K >> 5;  // BK = 32

  const int srow = wave * 16 + (lane >> 2);
  const int skg  = (lane & 3) ^ ((lane >> 3) & 3);
  const uint16_t* Ag0 = A  + (size_t)(m0 + srow) * K + skg * 8;
  const uint16_t* Ag1 = A  + (size_t)(m0 + 128 + srow) * K + skg * 8;
  const uint16_t* Bg0 = Bt + (size_t)(n0 + srow) * K + skg * 8;
  const uint16_t* Bg1 = Bt + (size_t)(n0 + 128 + srow) * K + skg * 8;
  const int sdw = wave * 512;

  const int kgq = (lane >> 4) ^ ((lane >> 1) & 3);
  const int rA = (wr * 128 + (lane & 15)) * 32 + kgq * 8;
  const int rB = (wc * 64  + (lane & 15)) * 32 + kgq * 8;

  f32x4 acc[8][4] = {};

#pragma unroll
  for (int tt = 0; tt < 3; ++tt) {
    uint16_t* sb = &lds[tt * 16384];
    gload_lds16(Ag0 + tt * 32, sb + sdw);
    gload_lds16(Ag1 + tt * 32, sb + 4096 + sdw);
    gload_lds16(Bg0 + tt * 32, sb + 8192 + sdw);
    gload_lds16(Bg1 + tt * 32, sb + 12288 + sdw);
  }

  for (int u = 0; u < NT; ++u) {
    const uint16_t* Ab = &lds[(u & 3) * 16384 + rA];
    const uint16_t* Bb = &lds[(u & 3) * 16384 + 8192 + rB];
    const int us = (u + 3 < NT) ? (u + 3) : (NT - 1);
    uint16_t* sb = &lds[((u + 3) & 3) * 16384];
    const size_t kofs = (size_t)us * 32;

    asm volatile("s_waitcnt vmcnt(8)" ::: "memory");
    __builtin_amdgcn_s_barrier();

    bf16x8 af0[4], af1[4], bfr[4];
#pragma unroll
    for (int m = 0; m < 4; ++m) af0[m] = *reinterpret_cast<const bf16x8*>(Ab + m * 512);
#pragma unroll
    for (int n = 0; n < 4; ++n) bfr[n] = *reinterpret_cast<const bf16x8*>(Bb + n * 512);
    gload_lds16(Ag0 + kofs, sb + sdw);
    gload_lds16(Ag1 + kofs, sb + 4096 + sdw);
    __builtin_amdgcn_sched_barrier(0);
    __builtin_amdgcn_s_barrier();
    asm volatile("s_waitcnt lgkmcnt(0)" ::: "memory");
    __builtin_amdgcn_sched_barrier(0);
    __builtin_amdgcn_s_setprio(1);
#pragma unroll
    for (int m = 0; m < 4; ++m)
#pragma unroll
      for (int n = 0; n < 4; ++n)
        acc[m][n] = __builtin_amdgcn_mfma_f32_16x16x32_bf16(bfr[n], af0[m], acc[m][n], 0, 0, 0);
    __builtin_amdgcn_s_setprio(0);
    __builtin_amdgcn_sched_barrier(0);

#pragma unroll
    for (int m = 0; m < 4; ++m) af1[m] = *reinterpret_cast<const bf16x8*>(Ab + (m + 4) * 512);
    gload_lds16(Bg0 + kofs, sb + 8192 + sdw);
    gload_lds16(Bg1 + kofs, sb + 12288 + sdw);
    __builtin_amdgcn_sched_barrier(0);
    __builtin_amdgcn_s_barrier();
    asm volatile("s_waitcnt lgkmcnt(0)" ::: "memory");
    __builtin_amdgcn_sched_barrier(0);
    __builtin_amdgcn_s_setprio(1);
#pragma unroll
    for (int m = 0; m < 4; ++m)
#pragma unroll
      for (int n = 0; n < 4; ++n)
        acc[m + 4][n] = __builtin_amdgcn_mfma_f32_16x16x32_bf16(bfr[n], af1[m], acc[m + 4][n], 0, 0, 0);
    __builtin_amdgcn_s_setprio(0);
    __builtin_amdgcn_sched_barrier(0);
  }
  asm volatile("s_waitcnt vmcnt(0)" ::: "memory");

  // ---- epilogue (operand-swapped layout):
  //   row = m0 + wr*128 + m*16 + (lane&15)
  //   col = n0 + wc*64 + n*16 + (lane>>4)*4 + i
  const int r0 = m0 + wr * 128 + (lane & 15);
  const int cb = n0 + wc * 64 + (lane >> 4) * 4;
  if constexpr (OUT_BF16_BIAS) {
    uint16_t* C = (uint16_t*)Cout;
    float bv[4][4];
#pragma unroll
    for (int n = 0; n < 4; ++n) {
      const float4 b4 = *reinterpret_cast<const float4*>(&bias[cb + n * 16]);
      bv[n][0] = b4.x; bv[n][1] = b4.y; bv[n][2] = b4.z; bv[n][3] = b4.w;
    }
#pragma unroll
    for (int m = 0; m < 8; ++m) {
      const int row = r0 + m * 16;
#pragma unroll
      for (int n = 0; n < 4; ++n) {
        const int col = cb + n * 16;
        ushort4 o;
        o.x = f32_to_bf16(acc[m][n][0] + bv[n][0]);
        o.y = f32_to_bf16(acc[m][n][1] + bv[n][1]);
        o.z = f32_to_bf16(acc[m][n][2] + bv[n][2]);
        o.w = f32_to_bf16(acc[m][n][3] + bv[n][3]);
        *reinterpret_cast<ushort4*>(&C[(size_t)row * N + col]) = o;
      }
    }

    if constexpr (FUSE_SCAN) {
      // In-register chunk summaries. Wave wr holds chunk 2wr+half rows as
      // (m = half*4+mm, l15 = lane&15); lane's 4 cols = 2 (kz,hx) pairs.
      // Affine compose (later T2 after earlier T1): (a,v) = (a1*a2, a2*v1+v2).
      const int l15 = lane & 15;
      const int b   = m0 >> 12;              // batch (T=4096, tile never crosses)
      const int E2  = N >> 1;
#pragma unroll
      for (int half = 0; half < 2; ++half) {
        const int c = ((m0 & 4095) >> 6) + wr * 2 + half;  // chunk in batch
        const size_t obase = ((size_t)(b * 64 + c)) * E2;
#pragma unroll
        for (int n = 0; n < 4; ++n) {
#pragma unroll
          for (int p = 0; p < 2; ++p) {
            float Ar = 1.0f, Vr = 0.0f;
#pragma unroll
            for (int mm = 0; mm < 4; ++mm) {
              const int m = half * 4 + mm;
              // identical inputs to pass3: round to bf16 grid first
              float kz = bf16r(acc[m][n][2 * p]     + bv[n][2 * p]);
              float hx = bf16r(acc[m][n][2 * p + 1] + bv[n][2 * p + 1]);
              float a, v; gate_val(kz, hx, a, v);
              // 16-lane inclusive affine scan over l15 (row order)
#pragma unroll
              for (int d = 1; d < 16; d <<= 1) {
                float au = __shfl_up(a, d, 16);
                float vu = __shfl_up(v, d, 16);
                if (l15 >= d) { v = a * vu + v; a = a * au; }
              }
              // segment total (rows l15=0..15 of this m) lives at l15==15
              float As = __shfl(a, 15, 16);
              float Vs = __shfl(v, 15, 16);
              Vr = As * Vr + Vs;   // compose after running prefix
              Ar = Ar * As;
            }
            if (l15 == 15) {
              const int e = (n0 >> 1) + wc * 32 + ((lane >> 4) << 1) + n * 8 + p;
              Ac[obase + e] = Ar;
              Vc[obase + e] = Vr;
            }
          }
        }
      }
    }
  } else {
    float* C = (float*)Cout;
#pragma unroll
    for (int m = 0; m < 8; ++m) {
      const int row = r0 + m * 16;
#pragma unroll
      for (int n = 0; n < 4; ++n) {
        const int col = cb + n * 16;
        float4 o;
        o.x = acc[m][n][0]; o.y = acc[m][n][1];
        o.z = acc[m][n][2]; o.w = acc[m][n][3];
        *reinterpret_cast<float4*>(&C[(size_t)row * N + col]) = o;
      }
    }
  }
}

// pass3: replay chunks with true h_start (scans predecessor summaries first).
__global__ __launch_bounds__(256) void scan_pass3(
    const uint16_t* __restrict__ proj, const float* __restrict__ Ac,
    const float* __restrict__ Vc, uint16_t* __restrict__ hout,
    int T, int E, int CH, int L) {
  const int e = blockIdx.x * 256 + threadIdx.x;
  const int c = blockIdx.y;
  const int b = blockIdx.z;
  const int N1 = 2 * E;
  float h = 0.5f;  // h_0 = g(0)
  for (int cc = 0; cc < c; ++cc) {
    const size_t idx = ((size_t)(b * CH + cc)) * E + e;
    h = Ac[idx] * h + Vc[idx];
  }
  const uint16_t* p = proj + (size_t)(b * T + c * L) * N1 + 2 * e;
  uint16_t* o = hout + (size_t)(b * T + c * L) * E + e;
#pragma unroll 4
  for (int t = 0; t < L; ++t) {
    float a, v; gate_from_u32(*reinterpret_cast<const uint32_t*>(p), a, v);
    h = a * h + v;
    *o = f32_to_bf16(h);
    p += N1; o += E;
  }
}

extern "C" void kernel_launch(void* const* d_in, const int* in_sizes, int n_in,
                              void* d_out, int out_size, void* d_ws, size_t ws_size,
                              hipStream_t stream) {
  const float* x   = (const float*)d_in[0];
  const float* W_f = (const float*)d_in[1];
  const float* b_f = (const float*)d_in[2];
  const float* W_d = (const float*)d_in[3];
  const int Bb = 4, T = 4096, D = 1024, E = 1536;
  const int M = Bb * T;        // 16384
  const int N1 = 2 * E;        // 3072
  const int CH = 64, L = T / CH;

  char* w = (char*)d_ws;
  uint16_t* x_bf  = (uint16_t*)w; w += (size_t)M * D * 2;
  uint16_t* Wf_bf = (uint16_t*)w; w += (size_t)N1 * D * 2;
  uint16_t* Wd_bf = (uint16_t*)w; w += (size_t)D * E * 2;
  uint16_t* proj  = (uint16_t*)w; w += (size_t)M * N1 * 2;
  uint16_t* h_bf  = (uint16_t*)w; w += (size_t)M * E * 2;
  float* Ac     = (float*)w; w += (size_t)Bb * CH * E * 4;
  float* Vc     = (float*)w; w += (size_t)Bb * CH * E * 4;
  float* bias_p = (float*)w; w += (size_t)N1 * 4;

  cast_all<<<2048, 256, 0, stream>>>(x, x_bf, W_f, Wf_bf, b_f, bias_p, W_d, Wd_bf);

  // proj = x @ Wf_perm^T + bias_p (bf16, interleaved cols) + in-reg summaries
  gemm256<1, 1><<<(M / 256) * (N1 / 256), 512, 0, stream>>>(
      x_bf, Wf_bf, bias_p, proj, Ac, Vc, M, N1, D);

  scan_pass3<<<dim3(E / 256, CH, Bb), 256, 0, stream>>>(proj, Ac, Vc, h_bf, T, E, CH, L);

  // out = h @ W_down^T (fp32 out)
  gemm256<0, 0><<<(M / 256) * (D / 256), 512, 0, stream>>>(
      h_bf, Wd_bf, nullptr, d_out, nullptr, nullptr, M, D, E);
}

// Round 12
// 269.511 us; speedup vs baseline: 1.1864x; 1.0732x over previous
//
#include <hip/hip_runtime.h>
#include <hip/hip_bf16.h>
#include <stdint.h>

// minGRU: proj = x@W_f^T + b_f (bf16 GEMM; chunk summaries via LDS-transpose
// scan in epilogue) -> chunked scan replay -> out = h@W_down^T.
// B=4 T=4096 D=1024 E=1536.
// GEMM (R6/R8-verified): 256x256, BK=32, 8 waves, 4-deep LDS ring, vmcnt(8),
// 2 phases/iter {reads -> raw barrier -> lgkmcnt(0) AFTER -> 16 MFMA},
// T2 XOR swizzle, operand-swapped epilogue, L2-patch map.
// R12: epilogue stores gate pairs to LDS (128KB = exactly one 256x256 tile),
// then 512 threads do 1-thread-per-(chunk,e) serial scans (no global re-read
// [R10 fail: L2 eviction], no shuffles [R11 fail: 640 DS ops/lane]).

typedef __bf16 bf16x8 __attribute__((ext_vector_type(8)));
typedef float  f32x4  __attribute__((ext_vector_type(4)));

__device__ __forceinline__ uint16_t f32_to_bf16(float f) {
  union { float f; uint32_t u; } v; v.f = f;
  uint32_t r = (v.u + 0x7FFFu + ((v.u >> 16) & 1u)) >> 16;  // RNE
  return (uint16_t)r;
}
__device__ __forceinline__ float bf16_to_f32(uint16_t u) {
  union { uint32_t u; float f; } v; v.u = ((uint32_t)u) << 16;
  return v.f;
}

__device__ __forceinline__ void gload_lds16(const uint16_t* g, uint16_t* l) {
  __builtin_amdgcn_global_load_lds(
      (__attribute__((address_space(1))) void*)(g),
      (__attribute__((address_space(3))) void*)(l), 16, 0, 0);
}

// ---- gate math: h_t = a*h_{t-1} + v;  a = 1-sigmoid(kz), v = sigmoid(kz)*g(hx)
__device__ __forceinline__ void gate_val(float kz, float hx, float& a, float& v) {
  float ek = __expf(-fabsf(kz));
  float r  = 1.0f / (1.0f + ek);
  float z  = (kz >= 0.0f) ? r : ek * r;   // sigmoid(k)
  a        = (kz >= 0.0f) ? ek * r : r;   // 1 - sigmoid(k)
  float g;
  if (hx >= 0.0f) {
    g = hx + 0.5f;
  } else {
    float eh = __expf(hx);
    g = eh / (1.0f + eh);
  }
  v = z * g;
}
__device__ __forceinline__ void gate_from_u32(uint32_t u, float& a, float& v) {
  float kz = bf16_to_f32((uint16_t)(u & 0xFFFFu));
  float hx = bf16_to_f32((uint16_t)(u >> 16));
  gate_val(kz, hx, a, v);
}

__device__ __forceinline__ void cast4(const float* s, uint16_t* d, int j) {
  float4 v = reinterpret_cast<const float4*>(s)[j];
  ushort4 o;
  o.x = f32_to_bf16(v.x); o.y = f32_to_bf16(v.y);
  o.z = f32_to_bf16(v.z); o.w = f32_to_bf16(v.w);
  reinterpret_cast<ushort4*>(d)[j] = o;
}

// ---- fused cast: x, W_f (row-interleaved), W_down, bias (permuted) ----
__global__ __launch_bounds__(256) void cast_all(
    const float* __restrict__ x,   uint16_t* __restrict__ x_bf,
    const float* __restrict__ W_f, uint16_t* __restrict__ Wf_bf,
    const float* __restrict__ b_f, float* __restrict__ bias_p,
    const float* __restrict__ W_d, uint16_t* __restrict__ Wd_bf) {
  const int stride = gridDim.x * blockDim.x;
  const int gid = blockIdx.x * blockDim.x + threadIdx.x;
  if (gid < 3072)  // bias permute: col 2e <- b_f[e], col 2e+1 <- b_f[1536+e]
    bias_p[gid] = b_f[(gid & 1) ? 1536 + (gid >> 1) : (gid >> 1)];
  for (int i = gid; i < 4194304; i += stride) cast4(x, x_bf, i);
  for (int i = gid; i < 786432; i += stride) {
    const int r = i >> 8, cg = i & 255;
    const int rp = (r < 1536) ? (r << 1) : (((r - 1536) << 1) | 1);
    float4 v = reinterpret_cast<const float4*>(W_f)[i];
    ushort4 o;
    o.x = f32_to_bf16(v.x); o.y = f32_to_bf16(v.y);
    o.z = f32_to_bf16(v.z); o.w = f32_to_bf16(v.w);
    reinterpret_cast<ushort4*>(Wf_bf)[rp * 256 + cg] = o;
  }
  for (int i = gid; i < 393216; i += stride) cast4(W_d, Wd_bf, i);
}

// ---------------- bf16 GEMM, C = A(M,K) * Bt(N,K)^T, 256^2, ring-4 ----------
// (R6/R8-verified loop.)  FUSE_SCAN: epilogue mirrors the bf16 gate pairs into
// LDS (swizzled), then 512 threads run per-(chunk,e) serial scans -> Ac/Vc.
template <int OUT_BF16_BIAS, int FUSE_SCAN>
__global__ __launch_bounds__(512, 2) void gemm256(
    const uint16_t* __restrict__ A, const uint16_t* __restrict__ Bt,
    const float* __restrict__ bias, void* __restrict__ Cout,
    float* __restrict__ Ac, float* __restrict__ Vc,
    int M, int N, int K) {
  __shared__ alignas(16) uint16_t lds[4 * 16384];  // 128 KB

  const int tid  = threadIdx.x;
  const int wave = tid >> 6;
  const int lane = tid & 63;
  const int wr = wave >> 2;
  const int wc = wave & 3;

  // L2-fitting patch map (2m x 4n tiles per patch; XCD x = bid&7)
  const int bid = (int)blockIdx.x;
  const int xq  = bid & 7;
  const int j   = bid >> 3;
  const int pi  = xq + ((j >> 3) << 3);
  const int q   = j & 7;
  const int mt  = ((pi & 31) << 1) + (q >> 2);
  const int nt  = ((pi >> 5) << 2) + (q & 3);
  const int m0  = mt << 8;
  const int n0  = nt << 8;

  const int NT = K >> 5;  // BK = 32

  const int srow = wave * 16 + (lane >> 2);
  const int skg  = (lane & 3) ^ ((lane >> 3) & 3);
  const uint16_t* Ag0 = A  + (size_t)(m0 + srow) * K + skg * 8;
  const uint16_t* Ag1 = A  + (size_t)(m0 + 128 + srow) * K + skg * 8;
  const uint16_t* Bg0 = Bt + (size_t)(n0 + srow) * K + skg * 8;
  const uint16_t* Bg1 = Bt + (size_t)(n0 + 128 + srow) * K + skg * 8;
  const int sdw = wave * 512;

  const int kgq = (lane >> 4) ^ ((lane >> 1) & 3);
  const int rA = (wr * 128 + (lane & 15)) * 32 + kgq * 8;
  const int rB = (wc * 64  + (lane & 15)) * 32 + kgq * 8;

  f32x4 acc[8][4] = {};

#pragma unroll
  for (int tt = 0; tt < 3; ++tt) {
    uint16_t* sb = &lds[tt * 16384];
    gload_lds16(Ag0 + tt * 32, sb + sdw);
    gload_lds16(Ag1 + tt * 32, sb + 4096 + sdw);
    gload_lds16(Bg0 + tt * 32, sb + 8192 + sdw);
    gload_lds16(Bg1 + tt * 32, sb + 12288 + sdw);
  }

  for (int u = 0; u < NT; ++u) {
    const uint16_t* Ab = &lds[(u & 3) * 16384 + rA];
    const uint16_t* Bb = &lds[(u & 3) * 16384 + 8192 + rB];
    const int us = (u + 3 < NT) ? (u + 3) : (NT - 1);
    uint16_t* sb = &lds[((u + 3) & 3) * 16384];
    const size_t kofs = (size_t)us * 32;

    asm volatile("s_waitcnt vmcnt(8)" ::: "memory");
    __builtin_amdgcn_s_barrier();

    bf16x8 af0[4], af1[4], bfr[4];
#pragma unroll
    for (int m = 0; m < 4; ++m) af0[m] = *reinterpret_cast<const bf16x8*>(Ab + m * 512);
#pragma unroll
    for (int n = 0; n < 4; ++n) bfr[n] = *reinterpret_cast<const bf16x8*>(Bb + n * 512);
    gload_lds16(Ag0 + kofs, sb + sdw);
    gload_lds16(Ag1 + kofs, sb + 4096 + sdw);
    __builtin_amdgcn_sched_barrier(0);
    __builtin_amdgcn_s_barrier();
    asm volatile("s_waitcnt lgkmcnt(0)" ::: "memory");
    __builtin_amdgcn_sched_barrier(0);
    __builtin_amdgcn_s_setprio(1);
#pragma unroll
    for (int m = 0; m < 4; ++m)
#pragma unroll
      for (int n = 0; n < 4; ++n)
        acc[m][n] = __builtin_amdgcn_mfma_f32_16x16x32_bf16(bfr[n], af0[m], acc[m][n], 0, 0, 0);
    __builtin_amdgcn_s_setprio(0);
    __builtin_amdgcn_sched_barrier(0);

#pragma unroll
    for (int m = 0; m < 4; ++m) af1[m] = *reinterpret_cast<const bf16x8*>(Ab + (m + 4) * 512);
    gload_lds16(Bg0 + kofs, sb + 8192 + sdw);
    gload_lds16(Bg1 + kofs, sb + 12288 + sdw);
    __builtin_amdgcn_sched_barrier(0);
    __builtin_amdgcn_s_barrier();
    asm volatile("s_waitcnt lgkmcnt(0)" ::: "memory");
    __builtin_amdgcn_sched_barrier(0);
    __builtin_amdgcn_s_setprio(1);
#pragma unroll
    for (int m = 0; m < 4; ++m)
#pragma unroll
      for (int n = 0; n < 4; ++n)
        acc[m + 4][n] = __builtin_amdgcn_mfma_f32_16x16x32_bf16(bfr[n], af1[m], acc[m + 4][n], 0, 0, 0);
    __builtin_amdgcn_s_setprio(0);
    __builtin_amdgcn_sched_barrier(0);
  }
  asm volatile("s_waitcnt vmcnt(0)" ::: "memory");

  // ---- epilogue (operand-swapped layout):
  //   row = m0 + wr*128 + m*16 + (lane&15)
  //   col = n0 + wc*64 + n*16 + (lane>>4)*4 + i
  const int r0 = m0 + wr * 128 + (lane & 15);
  const int cb = n0 + wc * 64 + (lane >> 4) * 4;
  if constexpr (OUT_BF16_BIAS) {
    uint16_t* C = (uint16_t*)Cout;
    if constexpr (FUSE_SCAN) {
      // every wave passed vmcnt(0) (staging writes drained) and its final
      // lgkmcnt(0) (LDS reads drained) -> safe to repurpose LDS after barrier
      __builtin_amdgcn_s_barrier();
    }
    char* lb = (char*)lds;
    float bv[4][4];
#pragma unroll
    for (int n = 0; n < 4; ++n) {
      const float4 b4 = *reinterpret_cast<const float4*>(&bias[cb + n * 16]);
      bv[n][0] = b4.x; bv[n][1] = b4.y; bv[n][2] = b4.z; bv[n][3] = b4.w;
    }
#pragma unroll
    for (int m = 0; m < 8; ++m) {
      const int row = r0 + m * 16;
#pragma unroll
      for (int n = 0; n < 4; ++n) {
        const int col = cb + n * 16;
        ushort4 o;
        o.x = f32_to_bf16(acc[m][n][0] + bv[n][0]);
        o.y = f32_to_bf16(acc[m][n][1] + bv[n][1]);
        o.z = f32_to_bf16(acc[m][n][2] + bv[n][2]);
        o.w = f32_to_bf16(acc[m][n][3] + bv[n][3]);
        *reinterpret_cast<ushort4*>(&C[(size_t)row * N + col]) = o;
        if constexpr (FUSE_SCAN) {
          // local row lr (0..255); b64 slot (0..63); XOR spreads banks
          const int lr   = wr * 128 + m * 16 + (lane & 15);
          const int slot = wc * 16 + n * 4 + (lane >> 4);
          const int boff = lr * 512 + ((slot * 8) ^ ((lr & 15) << 3));
          uint2 pr;
          pr.x = (uint32_t)o.x | ((uint32_t)o.y << 16);
          pr.y = (uint32_t)o.z | ((uint32_t)o.w << 16);
          *reinterpret_cast<uint2*>(lb + boff) = pr;
        }
      }
    }

    if constexpr (FUSE_SCAN) {
      asm volatile("s_waitcnt lgkmcnt(0)" ::: "memory");
      __builtin_amdgcn_s_barrier();
      // 512 threads: one (chunk, e)-pair each; 64-step serial scan from LDS.
      const int cidx = tid >> 7;     // chunk within tile (L = 64)
      const int eloc = tid & 127;    // u32 pair index within row
      float Aa = 1.0f, Vv = 0.0f;
#pragma unroll 8
      for (int t = 0; t < 64; ++t) {
        const int lr   = cidx * 64 + t;
        const int boff = lr * 512 + ((((eloc >> 1) * 8) ^ ((lr & 15) << 3)) +
                                     (eloc & 1) * 4);
        uint32_t u32 = *reinterpret_cast<const uint32_t*>(lb + boff);
        float a, v; gate_from_u32(u32, a, v);
        Aa *= a;
        Vv = a * Vv + v;
      }
      const int b  = m0 >> 12;                   // batch (T = 4096)
      const int c  = ((m0 & 4095) >> 6) + cidx;  // chunk within batch
      const int E2 = N >> 1;
      const size_t idx = ((size_t)(b * 64 + c)) * E2 + (n0 >> 1) + eloc;
      Ac[idx] = Aa; Vc[idx] = Vv;
    }
  } else {
    float* C = (float*)Cout;
#pragma unroll
    for (int m = 0; m < 8; ++m) {
      const int row = r0 + m * 16;
#pragma unroll
      for (int n = 0; n < 4; ++n) {
        const int col = cb + n * 16;
        float4 o;
        o.x = acc[m][n][0]; o.y = acc[m][n][1];
        o.z = acc[m][n][2]; o.w = acc[m][n][3];
        *reinterpret_cast<float4*>(&C[(size_t)row * N + col]) = o;
      }
    }
  }
}

// pass3: replay chunks with true h_start (scans predecessor summaries first).
__global__ __launch_bounds__(256) void scan_pass3(
    const uint16_t* __restrict__ proj, const float* __restrict__ Ac,
    const float* __restrict__ Vc, uint16_t* __restrict__ hout,
    int T, int E, int CH, int L) {
  const int e = blockIdx.x * 256 + threadIdx.x;
  const int c = blockIdx.y;
  const int b = blockIdx.z;
  const int N1 = 2 * E;
  float h = 0.5f;  // h_0 = g(0)
  for (int cc = 0; cc < c; ++cc) {
    const size_t idx = ((size_t)(b * CH + cc)) * E + e;
    h = Ac[idx] * h + Vc[idx];
  }
  const uint16_t* p = proj + (size_t)(b * T + c * L) * N1 + 2 * e;
  uint16_t* o = hout + (size_t)(b * T + c * L) * E + e;
#pragma unroll 4
  for (int t = 0; t < L; ++t) {
    float a, v; gate_from_u32(*reinterpret_cast<const uint32_t*>(p), a, v);
    h = a * h + v;
    *o = f32_to_bf16(h);
    p += N1; o += E;
  }
}

extern "C" void kernel_launch(void* const* d_in, const int* in_sizes, int n_in,
                              void* d_out, int out_size, void* d_ws, size_t ws_size,
                              hipStream_t stream) {
  const float* x   = (const float*)d_in[0];
  const float* W_f = (const float*)d_in[1];
  const float* b_f = (const float*)d_in[2];
  const float* W_d = (const float*)d_in[3];
  const int Bb = 4, T = 4096, D = 1024, E = 1536;
  const int M = Bb * T;        // 16384
  const int N1 = 2 * E;        // 3072
  const int CH = 64, L = T / CH;

  char* w = (char*)d_ws;
  uint16_t* x_bf  = (uint16_t*)w; w += (size_t)M * D * 2;
  uint16_t* Wf_bf = (uint16_t*)w; w += (size_t)N1 * D * 2;
  uint16_t* Wd_bf = (uint16_t*)w; w += (size_t)D * E * 2;
  uint16_t* proj  = (uint16_t*)w; w += (size_t)M * N1 * 2;
  uint16_t* h_bf  = (uint16_t*)w; w += (size_t)M * E * 2;
  float* Ac     = (float*)w; w += (size_t)Bb * CH * E * 4;
  float* Vc     = (float*)w; w += (size_t)Bb * CH * E * 4;
  float* bias_p = (float*)w; w += (size_t)N1 * 4;

  cast_all<<<2048, 256, 0, stream>>>(x, x_bf, W_f, Wf_bf, b_f, bias_p, W_d, Wd_bf);

  // proj = x @ Wf_perm^T + bias_p (bf16, interleaved) + LDS-scan summaries
  gemm256<1, 1><<<(M / 256) * (N1 / 256), 512, 0, stream>>>(
      x_bf, Wf_bf, bias_p, proj, Ac, Vc, M, N1, D);

  scan_pass3<<<dim3(E / 256, CH, Bb), 256, 0, stream>>>(proj, Ac, Vc, h_bf, T, E, CH, L);

  // out = h @ W_down^T (fp32 out)
  gemm256<0, 0><<<(M / 256) * (D / 256), 512, 0, stream>>>(
      h_bf, Wd_bf, nullptr, d_out, nullptr, nullptr, M, D, E);
}

// Round 13
// 236.867 us; speedup vs baseline: 1.3499x; 1.1378x over previous
//
#include <hip/hip_runtime.h>
#include <hip/hip_bf16.h>
#include <stdint.h>

// minGRU: proj = x@W_f^T + b_f (bf16 GEMM; chunk summaries via LDS-transpose
// scan in epilogue) -> chunked scan replay -> out = h@W_down^T.
// B=4 T=4096 D=1024 E=1536.
// GEMM (R6/R8-verified): 256x256, BK=32, 8 waves, 4-deep LDS ring, vmcnt(8),
// 2 phases/iter {reads -> raw barrier -> lgkmcnt(0) AFTER -> 16 MFMA},
// T2 XOR swizzle, operand-swapped epilogue, L2-patch map.
// R12: epilogue LDS-transpose scan fusion (pass1 removed).
// R13: gate_val uses v_rcp (fast 1-ulp reciprocal) + branchless g(hx) --
// R12's +36us tail was full IEEE div sequences (~12 ops each) x 2 per gate,
// serialized at 1 block/CU.

typedef __bf16 bf16x8 __attribute__((ext_vector_type(8)));
typedef float  f32x4  __attribute__((ext_vector_type(4)));

__device__ __forceinline__ uint16_t f32_to_bf16(float f) {
  union { float f; uint32_t u; } v; v.f = f;
  uint32_t r = (v.u + 0x7FFFu + ((v.u >> 16) & 1u)) >> 16;  // RNE
  return (uint16_t)r;
}
__device__ __forceinline__ float bf16_to_f32(uint16_t u) {
  union { uint32_t u; float f; } v; v.u = ((uint32_t)u) << 16;
  return v.f;
}

__device__ __forceinline__ void gload_lds16(const uint16_t* g, uint16_t* l) {
  __builtin_amdgcn_global_load_lds(
      (__attribute__((address_space(1))) void*)(g),
      (__attribute__((address_space(3))) void*)(l), 16, 0, 0);
}

// ---- gate math: h_t = a*h_{t-1} + v;  a = 1-sigmoid(kz), v = sigmoid(kz)*g(hx)
// v_rcp_f32 (~1 ulp) instead of IEEE div: error << bf16 grid (2^-9).
__device__ __forceinline__ void gate_val(float kz, float hx, float& a, float& v) {
  float ek = __expf(-fabsf(kz));
  float r  = __builtin_amdgcn_rcpf(1.0f + ek);   // sigmoid(|k|)
  float z  = (kz >= 0.0f) ? r : ek * r;          // sigmoid(k)
  a        = (kz >= 0.0f) ? ek * r : r;          // 1 - sigmoid(k)
  float eh = __expf(fminf(hx, 0.0f));            // exp(hx) clamped (<=1)
  float g  = (hx >= 0.0f) ? (hx + 0.5f)
                          : eh * __builtin_amdgcn_rcpf(1.0f + eh);
  v = z * g;
}
__device__ __forceinline__ void gate_from_u32(uint32_t u, float& a, float& v) {
  float kz = bf16_to_f32((uint16_t)(u & 0xFFFFu));
  float hx = bf16_to_f32((uint16_t)(u >> 16));
  gate_val(kz, hx, a, v);
}

__device__ __forceinline__ void cast4(const float* s, uint16_t* d, int j) {
  float4 v = reinterpret_cast<const float4*>(s)[j];
  ushort4 o;
  o.x = f32_to_bf16(v.x); o.y = f32_to_bf16(v.y);
  o.z = f32_to_bf16(v.z); o.w = f32_to_bf16(v.w);
  reinterpret_cast<ushort4*>(d)[j] = o;
}

// ---- fused cast: x, W_f (row-interleaved), W_down, bias (permuted) ----
__global__ __launch_bounds__(256) void cast_all(
    const float* __restrict__ x,   uint16_t* __restrict__ x_bf,
    const float* __restrict__ W_f, uint16_t* __restrict__ Wf_bf,
    const float* __restrict__ b_f, float* __restrict__ bias_p,
    const float* __restrict__ W_d, uint16_t* __restrict__ Wd_bf) {
  const int stride = gridDim.x * blockDim.x;
  const int gid = blockIdx.x * blockDim.x + threadIdx.x;
  if (gid < 3072)  // bias permute: col 2e <- b_f[e], col 2e+1 <- b_f[1536+e]
    bias_p[gid] = b_f[(gid & 1) ? 1536 + (gid >> 1) : (gid >> 1)];
  for (int i = gid; i < 4194304; i += stride) cast4(x, x_bf, i);
  for (int i = gid; i < 786432; i += stride) {
    const int r = i >> 8, cg = i & 255;
    const int rp = (r < 1536) ? (r << 1) : (((r - 1536) << 1) | 1);
    float4 v = reinterpret_cast<const float4*>(W_f)[i];
    ushort4 o;
    o.x = f32_to_bf16(v.x); o.y = f32_to_bf16(v.y);
    o.z = f32_to_bf16(v.z); o.w = f32_to_bf16(v.w);
    reinterpret_cast<ushort4*>(Wf_bf)[rp * 256 + cg] = o;
  }
  for (int i = gid; i < 393216; i += stride) cast4(W_d, Wd_bf, i);
}

// ---------------- bf16 GEMM, C = A(M,K) * Bt(N,K)^T, 256^2, ring-4 ----------
// (R6/R8-verified loop.)  FUSE_SCAN: epilogue mirrors the bf16 gate pairs into
// LDS (swizzled), then 512 threads run per-(chunk,e) serial scans -> Ac/Vc.
template <int OUT_BF16_BIAS, int FUSE_SCAN>
__global__ __launch_bounds__(512, 2) void gemm256(
    const uint16_t* __restrict__ A, const uint16_t* __restrict__ Bt,
    const float* __restrict__ bias, void* __restrict__ Cout,
    float* __restrict__ Ac, float* __restrict__ Vc,
    int M, int N, int K) {
  __shared__ alignas(16) uint16_t lds[4 * 16384];  // 128 KB

  const int tid  = threadIdx.x;
  const int wave = tid >> 6;
  const int lane = tid & 63;
  const int wr = wave >> 2;
  const int wc = wave & 3;

  // L2-fitting patch map (2m x 4n tiles per patch; XCD x = bid&7)
  const int bid = (int)blockIdx.x;
  const int xq  = bid & 7;
  const int j   = bid >> 3;
  const int pi  = xq + ((j >> 3) << 3);
  const int q   = j & 7;
  const int mt  = ((pi & 31) << 1) + (q >> 2);
  const int nt  = ((pi >> 5) << 2) + (q & 3);
  const int m0  = mt << 8;
  const int n0  = nt << 8;

  const int NT = K >> 5;  // BK = 32

  const int srow = wave * 16 + (lane >> 2);
  const int skg  = (lane & 3) ^ ((lane >> 3) & 3);
  const uint16_t* Ag0 = A  + (size_t)(m0 + srow) * K + skg * 8;
  const uint16_t* Ag1 = A  + (size_t)(m0 + 128 + srow) * K + skg * 8;
  const uint16_t* Bg0 = Bt + (size_t)(n0 + srow) * K + skg * 8;
  const uint16_t* Bg1 = Bt + (size_t)(n0 + 128 + srow) * K + skg * 8;
  const int sdw = wave * 512;

  const int kgq = (lane >> 4) ^ ((lane >> 1) & 3);
  const int rA = (wr * 128 + (lane & 15)) * 32 + kgq * 8;
  const int rB = (wc * 64  + (lane & 15)) * 32 + kgq * 8;

  f32x4 acc[8][4] = {};

#pragma unroll
  for (int tt = 0; tt < 3; ++tt) {
    uint16_t* sb = &lds[tt * 16384];
    gload_lds16(Ag0 + tt * 32, sb + sdw);
    gload_lds16(Ag1 + tt * 32, sb + 4096 + sdw);
    gload_lds16(Bg0 + tt * 32, sb + 8192 + sdw);
    gload_lds16(Bg1 + tt * 32, sb + 12288 + sdw);
  }

  for (int u = 0; u < NT; ++u) {
    const uint16_t* Ab = &lds[(u & 3) * 16384 + rA];
    const uint16_t* Bb = &lds[(u & 3) * 16384 + 8192 + rB];
    const int us = (u + 3 < NT) ? (u + 3) : (NT - 1);
    uint16_t* sb = &lds[((u + 3) & 3) * 16384];
    const size_t kofs = (size_t)us * 32;

    asm volatile("s_waitcnt vmcnt(8)" ::: "memory");
    __builtin_amdgcn_s_barrier();

    bf16x8 af0[4], af1[4], bfr[4];
#pragma unroll
    for (int m = 0; m < 4; ++m) af0[m] = *reinterpret_cast<const bf16x8*>(Ab + m * 512);
#pragma unroll
    for (int n = 0; n < 4; ++n) bfr[n] = *reinterpret_cast<const bf16x8*>(Bb + n * 512);
    gload_lds16(Ag0 + kofs, sb + sdw);
    gload_lds16(Ag1 + kofs, sb + 4096 + sdw);
    __builtin_amdgcn_sched_barrier(0);
    __builtin_amdgcn_s_barrier();
    asm volatile("s_waitcnt lgkmcnt(0)" ::: "memory");
    __builtin_amdgcn_sched_barrier(0);
    __builtin_amdgcn_s_setprio(1);
#pragma unroll
    for (int m = 0; m < 4; ++m)
#pragma unroll
      for (int n = 0; n < 4; ++n)
        acc[m][n] = __builtin_amdgcn_mfma_f32_16x16x32_bf16(bfr[n], af0[m], acc[m][n], 0, 0, 0);
    __builtin_amdgcn_s_setprio(0);
    __builtin_amdgcn_sched_barrier(0);

#pragma unroll
    for (int m = 0; m < 4; ++m) af1[m] = *reinterpret_cast<const bf16x8*>(Ab + (m + 4) * 512);
    gload_lds16(Bg0 + kofs, sb + 8192 + sdw);
    gload_lds16(Bg1 + kofs, sb + 12288 + sdw);
    __builtin_amdgcn_sched_barrier(0);
    __builtin_amdgcn_s_barrier();
    asm volatile("s_waitcnt lgkmcnt(0)" ::: "memory");
    __builtin_amdgcn_sched_barrier(0);
    __builtin_amdgcn_s_setprio(1);
#pragma unroll
    for (int m = 0; m < 4; ++m)
#pragma unroll
      for (int n = 0; n < 4; ++n)
        acc[m + 4][n] = __builtin_amdgcn_mfma_f32_16x16x32_bf16(bfr[n], af1[m], acc[m + 4][n], 0, 0, 0);
    __builtin_amdgcn_s_setprio(0);
    __builtin_amdgcn_sched_barrier(0);
  }
  asm volatile("s_waitcnt vmcnt(0)" ::: "memory");

  // ---- epilogue (operand-swapped layout):
  //   row = m0 + wr*128 + m*16 + (lane&15)
  //   col = n0 + wc*64 + n*16 + (lane>>4)*4 + i
  const int r0 = m0 + wr * 128 + (lane & 15);
  const int cb = n0 + wc * 64 + (lane >> 4) * 4;
  if constexpr (OUT_BF16_BIAS) {
    uint16_t* C = (uint16_t*)Cout;
    if constexpr (FUSE_SCAN) {
      // every wave passed vmcnt(0) (staging writes drained) and its final
      // lgkmcnt(0) (LDS reads drained) -> safe to repurpose LDS after barrier
      __builtin_amdgcn_s_barrier();
    }
    char* lb = (char*)lds;
    float bv[4][4];
#pragma unroll
    for (int n = 0; n < 4; ++n) {
      const float4 b4 = *reinterpret_cast<const float4*>(&bias[cb + n * 16]);
      bv[n][0] = b4.x; bv[n][1] = b4.y; bv[n][2] = b4.z; bv[n][3] = b4.w;
    }
#pragma unroll
    for (int m = 0; m < 8; ++m) {
      const int row = r0 + m * 16;
#pragma unroll
      for (int n = 0; n < 4; ++n) {
        const int col = cb + n * 16;
        ushort4 o;
        o.x = f32_to_bf16(acc[m][n][0] + bv[n][0]);
        o.y = f32_to_bf16(acc[m][n][1] + bv[n][1]);
        o.z = f32_to_bf16(acc[m][n][2] + bv[n][2]);
        o.w = f32_to_bf16(acc[m][n][3] + bv[n][3]);
        *reinterpret_cast<ushort4*>(&C[(size_t)row * N + col]) = o;
        if constexpr (FUSE_SCAN) {
          // local row lr (0..255); b64 slot (0..63); XOR spreads banks
          const int lr   = wr * 128 + m * 16 + (lane & 15);
          const int slot = wc * 16 + n * 4 + (lane >> 4);
          const int boff = lr * 512 + ((slot * 8) ^ ((lr & 15) << 3));
          uint2 pr;
          pr.x = (uint32_t)o.x | ((uint32_t)o.y << 16);
          pr.y = (uint32_t)o.z | ((uint32_t)o.w << 16);
          *reinterpret_cast<uint2*>(lb + boff) = pr;
        }
      }
    }

    if constexpr (FUSE_SCAN) {
      asm volatile("s_waitcnt lgkmcnt(0)" ::: "memory");
      __builtin_amdgcn_s_barrier();
      // 512 threads: one (chunk, e)-pair each; 64-step serial scan from LDS.
      const int cidx = tid >> 7;     // chunk within tile (L = 64)
      const int eloc = tid & 127;    // u32 pair index within row
      float Aa = 1.0f, Vv = 0.0f;
#pragma unroll 8
      for (int t = 0; t < 64; ++t) {
        const int lr   = cidx * 64 + t;
        const int boff = lr * 512 + ((((eloc >> 1) * 8) ^ ((lr & 15) << 3)) +
                                     (eloc & 1) * 4);
        uint32_t u32 = *reinterpret_cast<const uint32_t*>(lb + boff);
        float a, v; gate_from_u32(u32, a, v);
        Aa *= a;
        Vv = a * Vv + v;
      }
      const int b  = m0 >> 12;                   // batch (T = 4096)
      const int c  = ((m0 & 4095) >> 6) + cidx;  // chunk within batch
      const int E2 = N >> 1;
      const size_t idx = ((size_t)(b * 64 + c)) * E2 + (n0 >> 1) + eloc;
      Ac[idx] = Aa; Vc[idx] = Vv;
    }
  } else {
    float* C = (float*)Cout;
#pragma unroll
    for (int m = 0; m < 8; ++m) {
      const int row = r0 + m * 16;
#pragma unroll
      for (int n = 0; n < 4; ++n) {
        const int col = cb + n * 16;
        float4 o;
        o.x = acc[m][n][0]; o.y = acc[m][n][1];
        o.z = acc[m][n][2]; o.w = acc[m][n][3];
        *reinterpret_cast<float4*>(&C[(size_t)row * N + col]) = o;
      }
    }
  }
}

// pass3: replay chunks with true h_start (scans predecessor summaries first).
__global__ __launch_bounds__(256) void scan_pass3(
    const uint16_t* __restrict__ proj, const float* __restrict__ Ac,
    const float* __restrict__ Vc, uint16_t* __restrict__ hout,
    int T, int E, int CH, int L) {
  const int e = blockIdx.x * 256 + threadIdx.x;
  const int c = blockIdx.y;
  const int b = blockIdx.z;
  const int N1 = 2 * E;
  float h = 0.5f;  // h_0 = g(0)
  for (int cc = 0; cc < c; ++cc) {
    const size_t idx = ((size_t)(b * CH + cc)) * E + e;
    h = Ac[idx] * h + Vc[idx];
  }
  const uint16_t* p = proj + (size_t)(b * T + c * L) * N1 + 2 * e;
  uint16_t* o = hout + (size_t)(b * T + c * L) * E + e;
#pragma unroll 4
  for (int t = 0; t < L; ++t) {
    float a, v; gate_from_u32(*reinterpret_cast<const uint32_t*>(p), a, v);
    h = a * h + v;
    *o = f32_to_bf16(h);
    p += N1; o += E;
  }
}

extern "C" void kernel_launch(void* const* d_in, const int* in_sizes, int n_in,
                              void* d_out, int out_size, void* d_ws, size_t ws_size,
                              hipStream_t stream) {
  const float* x   = (const float*)d_in[0];
  const float* W_f = (const float*)d_in[1];
  const float* b_f = (const float*)d_in[2];
  const float* W_d = (const float*)d_in[3];
  const int Bb = 4, T = 4096, D = 1024, E = 1536;
  const int M = Bb * T;        // 16384
  const int N1 = 2 * E;        // 3072
  const int CH = 64, L = T / CH;

  char* w = (char*)d_ws;
  uint16_t* x_bf  = (uint16_t*)w; w += (size_t)M * D * 2;
  uint16_t* Wf_bf = (uint16_t*)w; w += (size_t)N1 * D * 2;
  uint16_t* Wd_bf = (uint16_t*)w; w += (size_t)D * E * 2;
  uint16_t* proj  = (uint16_t*)w; w += (size_t)M * N1 * 2;
  uint16_t* h_bf  = (uint16_t*)w; w += (size_t)M * E * 2;
  float* Ac     = (float*)w; w += (size_t)Bb * CH * E * 4;
  float* Vc     = (float*)w; w += (size_t)Bb * CH * E * 4;
  float* bias_p = (float*)w; w += (size_t)N1 * 4;

  cast_all<<<2048, 256, 0, stream>>>(x, x_bf, W_f, Wf_bf, b_f, bias_p, W_d, Wd_bf);

  // proj = x @ Wf_perm^T + bias_p (bf16, interleaved) + LDS-scan summaries
  gemm256<1, 1><<<(M / 256) * (N1 / 256), 512, 0, stream>>>(
      x_bf, Wf_bf, bias_p, proj, Ac, Vc, M, N1, D);

  scan_pass3<<<dim3(E / 256, CH, Bb), 256, 0, stream>>>(proj, Ac, Vc, h_bf, T, E, CH, L);

  // out = h @ W_down^T (fp32 out)
  gemm256<0, 0><<<(M / 256) * (D / 256), 512, 0, stream>>>(
      h_bf, Wd_bf, nullptr, d_out, nullptr, nullptr, M, D, E);
}

// Round 14
// 233.507 us; speedup vs baseline: 1.3693x; 1.0144x over previous
//
#include <hip/hip_runtime.h>
#include <hip/hip_bf16.h>
#include <stdint.h>

// minGRU: proj = x@W_f^T + b_f (bf16 GEMM; chunk summaries via LDS-transpose
// scan in epilogue) -> chunked scan replay -> out = h@W_down^T.
// B=4 T=4096 D=1024 E=1536.
// R14 GEMM: 256x256 tile, BK=64, 8 waves, 2-deep LDS ring (2 x 64KB),
// ONE fence (vmcnt(0)+barrier) per 64-K iter (half the fences of BK=32),
// 4 phases/iter {reads -> raw barrier -> lgkmcnt(0) AFTER -> 16 MFMA},
// front-loaded staging (A in ph0, B in ph1), 8-slot XOR swizzle,
// operand-swapped epilogue, L2-patch map. FUSE_SCAN tail unchanged (R12/R13).

typedef __bf16 bf16x8 __attribute__((ext_vector_type(8)));
typedef float  f32x4  __attribute__((ext_vector_type(4)));

__device__ __forceinline__ uint16_t f32_to_bf16(float f) {
  union { float f; uint32_t u; } v; v.f = f;
  uint32_t r = (v.u + 0x7FFFu + ((v.u >> 16) & 1u)) >> 16;  // RNE
  return (uint16_t)r;
}
__device__ __forceinline__ float bf16_to_f32(uint16_t u) {
  union { uint32_t u; float f; } v; v.u = ((uint32_t)u) << 16;
  return v.f;
}

__device__ __forceinline__ void gload_lds16(const uint16_t* g, uint16_t* l) {
  __builtin_amdgcn_global_load_lds(
      (__attribute__((address_space(1))) void*)(g),
      (__attribute__((address_space(3))) void*)(l), 16, 0, 0);
}

// ---- gate math: h_t = a*h_{t-1} + v;  a = 1-sigmoid(kz), v = sigmoid(kz)*g(hx)
// v_rcp_f32 (~1 ulp): error << bf16 grid (2^-9).
__device__ __forceinline__ void gate_val(float kz, float hx, float& a, float& v) {
  float ek = __expf(-fabsf(kz));
  float r  = __builtin_amdgcn_rcpf(1.0f + ek);   // sigmoid(|k|)
  float z  = (kz >= 0.0f) ? r : ek * r;          // sigmoid(k)
  a        = (kz >= 0.0f) ? ek * r : r;          // 1 - sigmoid(k)
  float eh = __expf(fminf(hx, 0.0f));            // exp(hx) clamped (<=1)
  float g  = (hx >= 0.0f) ? (hx + 0.5f)
                          : eh * __builtin_amdgcn_rcpf(1.0f + eh);
  v = z * g;
}
__device__ __forceinline__ void gate_from_u32(uint32_t u, float& a, float& v) {
  float kz = bf16_to_f32((uint16_t)(u & 0xFFFFu));
  float hx = bf16_to_f32((uint16_t)(u >> 16));
  gate_val(kz, hx, a, v);
}

__device__ __forceinline__ void cast4(const float* s, uint16_t* d, int j) {
  float4 v = reinterpret_cast<const float4*>(s)[j];
  ushort4 o;
  o.x = f32_to_bf16(v.x); o.y = f32_to_bf16(v.y);
  o.z = f32_to_bf16(v.z); o.w = f32_to_bf16(v.w);
  reinterpret_cast<ushort4*>(d)[j] = o;
}

// ---- fused cast: x, W_f (row-interleaved), W_down, bias (permuted) ----
__global__ __launch_bounds__(256) void cast_all(
    const float* __restrict__ x,   uint16_t* __restrict__ x_bf,
    const float* __restrict__ W_f, uint16_t* __restrict__ Wf_bf,
    const float* __restrict__ b_f, float* __restrict__ bias_p,
    const float* __restrict__ W_d, uint16_t* __restrict__ Wd_bf) {
  const int stride = gridDim.x * blockDim.x;
  const int gid = blockIdx.x * blockDim.x + threadIdx.x;
  if (gid < 3072)  // bias permute: col 2e <- b_f[e], col 2e+1 <- b_f[1536+e]
    bias_p[gid] = b_f[(gid & 1) ? 1536 + (gid >> 1) : (gid >> 1)];
  for (int i = gid; i < 4194304; i += stride) cast4(x, x_bf, i);
  for (int i = gid; i < 786432; i += stride) {
    const int r = i >> 8, cg = i & 255;
    const int rp = (r < 1536) ? (r << 1) : (((r - 1536) << 1) | 1);
    float4 v = reinterpret_cast<const float4*>(W_f)[i];
    ushort4 o;
    o.x = f32_to_bf16(v.x); o.y = f32_to_bf16(v.y);
    o.z = f32_to_bf16(v.z); o.w = f32_to_bf16(v.w);
    reinterpret_cast<ushort4*>(Wf_bf)[rp * 256 + cg] = o;
  }
  for (int i = gid; i < 393216; i += stride) cast4(W_d, Wd_bf, i);
}

// ---------------- bf16 GEMM, C = A(M,K) * Bt(N,K)^T, 256^2, BK=64 ring-2 ----
// Requires M == 16384 (64 m-tiles), N % 1024 == 0, K % 64 == 0.
// LDS buf (64KB): A rows 0-255 at [0,16384) elems, B at [16384,32768).
// Row = 64 elems (128B), 8 slots x 8 elems; slot s of row r holds k-group
// s ^ (r&7)  (XOR swizzle; writer pre-swizzles the GLOBAL source per m104).
// Iter u: fence{vmcnt(0); barrier} (tile u landed; all prior reads consumed);
// ph0{rd ks0 A0-3,B0-3; stage A(u+1) x4; bar; lgkm(0); 16 MFMA}
// ph1{rd ks0 A4-7;      stage B(u+1) x4; bar; lgkm(0); 16 MFMA}
// ph2{rd ks1 A0-3,B0-3;                  bar; lgkm(0); 16 MFMA}
// ph3{rd ks1 A4-7;                       bar; lgkm(0); 16 MFMA}
// WAR: stage targets buf[(u+1)&1]=buf[(u-1)&1]; every wave drained its tile
// u-1 reads (its ph3 lgkmcnt(0)) before this fence barrier. RAW: vmcnt(0).
// Last gload issues ~2.5 phases before the fence that waits on it.
template <int OUT_BF16_BIAS, int FUSE_SCAN>
__global__ __launch_bounds__(512, 2) void gemm256(
    const uint16_t* __restrict__ A, const uint16_t* __restrict__ Bt,
    const float* __restrict__ bias, void* __restrict__ Cout,
    float* __restrict__ Ac, float* __restrict__ Vc,
    int M, int N, int K) {
  __shared__ alignas(16) uint16_t lds[2 * 32768];  // 128 KB

  const int tid  = threadIdx.x;
  const int wave = tid >> 6;
  const int lane = tid & 63;
  const int wr = wave >> 2;
  const int wc = wave & 3;

  // L2-fitting patch map (2m x 4n tiles per patch; XCD x = bid&7)
  const int bid = (int)blockIdx.x;
  const int xq  = bid & 7;
  const int j   = bid >> 3;
  const int pi  = xq + ((j >> 3) << 3);
  const int q   = j & 7;
  const int mt  = ((pi & 31) << 1) + (q >> 2);
  const int nt  = ((pi >> 5) << 2) + (q & 3);
  const int m0  = mt << 8;
  const int n0  = nt << 8;

  const int NT2 = K >> 6;  // BK = 64

  // staging: linear LDS dest (slot = lane&7), inverse-swizzled global source
  const int srow8 = wave * 8 + (lane >> 3);              // row within 64-row group
  const int skg   = (lane & 7) ^ ((lane >> 3) & 7);      // global k-group
  const uint16_t* Ag[4];
  const uint16_t* Bg[4];
#pragma unroll
  for (int r = 0; r < 4; ++r) {
    Ag[r] = A  + (size_t)(m0 + r * 64 + srow8) * K + skg * 8;
    Bg[r] = Bt + (size_t)(n0 + r * 64 + srow8) * K + skg * 8;
  }
  const int sdw = wave * 512;  // elems (wave-uniform LDS dest base)

  // swizzled read bases (elems): row*64 + ((kg ^ (row&7))<<3), row&7 = lane&7
  const int rowA = (wr * 128 + (lane & 15)) * 64;
  const int rowB = (wc * 64  + (lane & 15)) * 64;
  const int sl0  = ((lane >> 4) ^ (lane & 7)) << 3;         // ks0 slots
  const int sl1  = (((lane >> 4) ^ 4) ^ (lane & 7)) << 3;   // ks1 (kg|4)
  const int rA0 = rowA + sl0, rA1 = rowA + sl1;
  const int rB0 = rowB + sl0, rB1 = rowB + sl1;

  f32x4 acc[8][4] = {};

  // prologue: stage tile 0 (8 gloads)
#pragma unroll
  for (int r = 0; r < 4; ++r) {
    gload_lds16(Ag[r], &lds[r * 4096 + sdw]);
    gload_lds16(Bg[r], &lds[16384 + r * 4096 + sdw]);
  }

  for (int u = 0; u < NT2; ++u) {
    const uint16_t* Ab = &lds[(u & 1) * 32768];
    const uint16_t* Bb = Ab + 16384;
    const int ts = (u + 1 < NT2) ? (u + 1) : (NT2 - 1);  // clamp: uniform vmcnt
    uint16_t* sb = &lds[((u + 1) & 1) * 32768];
    const size_t kofs = (size_t)ts * 64;

    // fence: tile u landed (8 loads drained); all waves consumed tile u-1
    asm volatile("s_waitcnt vmcnt(0)" ::: "memory");
    __builtin_amdgcn_s_barrier();

    bf16x8 af0[4], af1[4], bfr[4];
    // ---- ph0: ks0 A0-3 + B0-3; stage A(u+1) ----
#pragma unroll
    for (int m = 0; m < 4; ++m) af0[m] = *reinterpret_cast<const bf16x8*>(Ab + rA0 + m * 1024);
#pragma unroll
    for (int n = 0; n < 4; ++n) bfr[n] = *reinterpret_cast<const bf16x8*>(Bb + rB0 + n * 1024);
#pragma unroll
    for (int r = 0; r < 4; ++r) gload_lds16(Ag[r] + kofs, sb + r * 4096 + sdw);
    __builtin_amdgcn_sched_barrier(0);
    __builtin_amdgcn_s_barrier();
    asm volatile("s_waitcnt lgkmcnt(0)" ::: "memory");
    __builtin_amdgcn_sched_barrier(0);
    __builtin_amdgcn_s_setprio(1);
#pragma unroll
    for (int m = 0; m < 4; ++m)
#pragma unroll
      for (int n = 0; n < 4; ++n)
        acc[m][n] = __builtin_amdgcn_mfma_f32_16x16x32_bf16(bfr[n], af0[m], acc[m][n], 0, 0, 0);
    __builtin_amdgcn_s_setprio(0);
    __builtin_amdgcn_sched_barrier(0);

    // ---- ph1: ks0 A4-7; stage B(u+1) ----
#pragma unroll
    for (int m = 0; m < 4; ++m) af1[m] = *reinterpret_cast<const bf16x8*>(Ab + rA0 + (m + 4) * 1024);
#pragma unroll
    for (int r = 0; r < 4; ++r) gload_lds16(Bg[r] + kofs, sb + 16384 + r * 4096 + sdw);
    __builtin_amdgcn_sched_barrier(0);
    __builtin_amdgcn_s_barrier();
    asm volatile("s_waitcnt lgkmcnt(0)" ::: "memory");
    __builtin_amdgcn_sched_barrier(0);
    __builtin_amdgcn_s_setprio(1);
#pragma unroll
    for (int m = 0; m < 4; ++m)
#pragma unroll
      for (int n = 0; n < 4; ++n)
        acc[m + 4][n] = __builtin_amdgcn_mfma_f32_16x16x32_bf16(bfr[n], af1[m], acc[m + 4][n], 0, 0, 0);
    __builtin_amdgcn_s_setprio(0);
    __builtin_amdgcn_sched_barrier(0);

    // ---- ph2: ks1 A0-3 + B0-3 ----
#pragma unroll
    for (int m = 0; m < 4; ++m) af0[m] = *reinterpret_cast<const bf16x8*>(Ab + rA1 + m * 1024);
#pragma unroll
    for (int n = 0; n < 4; ++n) bfr[n] = *reinterpret_cast<const bf16x8*>(Bb + rB1 + n * 1024);
    __builtin_amdgcn_sched_barrier(0);
    __builtin_amdgcn_s_barrier();
    asm volatile("s_waitcnt lgkmcnt(0)" ::: "memory");
    __builtin_amdgcn_sched_barrier(0);
    __builtin_amdgcn_s_setprio(1);
#pragma unroll
    for (int m = 0; m < 4; ++m)
#pragma unroll
      for (int n = 0; n < 4; ++n)
        acc[m][n] = __builtin_amdgcn_mfma_f32_16x16x32_bf16(bfr[n], af0[m], acc[m][n], 0, 0, 0);
    __builtin_amdgcn_s_setprio(0);
    __builtin_amdgcn_sched_barrier(0);

    // ---- ph3: ks1 A4-7 ----
#pragma unroll
    for (int m = 0; m < 4; ++m) af1[m] = *reinterpret_cast<const bf16x8*>(Ab + rA1 + (m + 4) * 1024);
    __builtin_amdgcn_sched_barrier(0);
    __builtin_amdgcn_s_barrier();
    asm volatile("s_waitcnt lgkmcnt(0)" ::: "memory");
    __builtin_amdgcn_sched_barrier(0);
    __builtin_amdgcn_s_setprio(1);
#pragma unroll
    for (int m = 0; m < 4; ++m)
#pragma unroll
      for (int n = 0; n < 4; ++n)
        acc[m + 4][n] = __builtin_amdgcn_mfma_f32_16x16x32_bf16(bfr[n], af1[m], acc[m + 4][n], 0, 0, 0);
    __builtin_amdgcn_s_setprio(0);
    __builtin_amdgcn_sched_barrier(0);
  }
  asm volatile("s_waitcnt vmcnt(0)" ::: "memory");  // drain redundant last stage

  // ---- epilogue (operand-swapped layout):
  //   row = m0 + wr*128 + m*16 + (lane&15)
  //   col = n0 + wc*64 + n*16 + (lane>>4)*4 + i
  const int r0 = m0 + wr * 128 + (lane & 15);
  const int cb = n0 + wc * 64 + (lane >> 4) * 4;
  if constexpr (OUT_BF16_BIAS) {
    uint16_t* C = (uint16_t*)Cout;
    if constexpr (FUSE_SCAN) {
      // every wave passed vmcnt(0) and its ph3 lgkmcnt(0) -> LDS reusable
      __builtin_amdgcn_s_barrier();
    }
    char* lb = (char*)lds;
    float bv[4][4];
#pragma unroll
    for (int n = 0; n < 4; ++n) {
      const float4 b4 = *reinterpret_cast<const float4*>(&bias[cb + n * 16]);
      bv[n][0] = b4.x; bv[n][1] = b4.y; bv[n][2] = b4.z; bv[n][3] = b4.w;
    }
#pragma unroll
    for (int m = 0; m < 8; ++m) {
      const int row = r0 + m * 16;
#pragma unroll
      for (int n = 0; n < 4; ++n) {
        const int col = cb + n * 16;
        ushort4 o;
        o.x = f32_to_bf16(acc[m][n][0] + bv[n][0]);
        o.y = f32_to_bf16(acc[m][n][1] + bv[n][1]);
        o.z = f32_to_bf16(acc[m][n][2] + bv[n][2]);
        o.w = f32_to_bf16(acc[m][n][3] + bv[n][3]);
        *reinterpret_cast<ushort4*>(&C[(size_t)row * N + col]) = o;
        if constexpr (FUSE_SCAN) {
          // local row lr (0..255); b64 slot (0..63); XOR spreads banks
          const int lr   = wr * 128 + m * 16 + (lane & 15);
          const int slot = wc * 16 + n * 4 + (lane >> 4);
          const int boff = lr * 512 + ((slot * 8) ^ ((lr & 15) << 3));
          uint2 pr;
          pr.x = (uint32_t)o.x | ((uint32_t)o.y << 16);
          pr.y = (uint32_t)o.z | ((uint32_t)o.w << 16);
          *reinterpret_cast<uint2*>(lb + boff) = pr;
        }
      }
    }

    if constexpr (FUSE_SCAN) {
      asm volatile("s_waitcnt lgkmcnt(0)" ::: "memory");
      __builtin_amdgcn_s_barrier();
      // 512 threads: one (chunk, e)-pair each; 64-step serial scan from LDS.
      const int cidx = tid >> 7;     // chunk within tile (L = 64)
      const int eloc = tid & 127;    // u32 pair index within row
      float Aa = 1.0f, Vv = 0.0f;
#pragma unroll 8
      for (int t = 0; t < 64; ++t) {
        const int lr   = cidx * 64 + t;
        const int boff = lr * 512 + ((((eloc >> 1) * 8) ^ ((lr & 15) << 3)) +
                                     (eloc & 1) * 4);
        uint32_t u32 = *reinterpret_cast<const uint32_t*>(lb + boff);
        float a, v; gate_from_u32(u32, a, v);
        Aa *= a;
        Vv = a * Vv + v;
      }
      const int b  = m0 >> 12;                   // batch (T = 4096)
      const int c  = ((m0 & 4095) >> 6) + cidx;  // chunk within batch
      const int E2 = N >> 1;
      const size_t idx = ((size_t)(b * 64 + c)) * E2 + (n0 >> 1) + eloc;
      Ac[idx] = Aa; Vc[idx] = Vv;
    }
  } else {
    float* C = (float*)Cout;
#pragma unroll
    for (int m = 0; m < 8; ++m) {
      const int row = r0 + m * 16;
#pragma unroll
      for (int n = 0; n < 4; ++n) {
        const int col = cb + n * 16;
        float4 o;
        o.x = acc[m][n][0]; o.y = acc[m][n][1];
        o.z = acc[m][n][2]; o.w = acc[m][n][3];
        *reinterpret_cast<float4*>(&C[(size_t)row * N + col]) = o;
      }
    }
  }
}

// pass3: replay chunks with true h_start (scans predecessor summaries first).
__global__ __launch_bounds__(256) void scan_pass3(
    const uint16_t* __restrict__ proj, const float* __restrict__ Ac,
    const float* __restrict__ Vc, uint16_t* __restrict__ hout,
    int T, int E, int CH, int L) {
  const int e = blockIdx.x * 256 + threadIdx.x;
  const int c = blockIdx.y;
  const int b = blockIdx.z;
  const int N1 = 2 * E;
  float h = 0.5f;  // h_0 = g(0)
  for (int cc = 0; cc < c; ++cc) {
    const size_t idx = ((size_t)(b * CH + cc)) * E + e;
    h = Ac[idx] * h + Vc[idx];
  }
  const uint16_t* p = proj + (size_t)(b * T + c * L) * N1 + 2 * e;
  uint16_t* o = hout + (size_t)(b * T + c * L) * E + e;
#pragma unroll 4
  for (int t = 0; t < L; ++t) {
    float a, v; gate_from_u32(*reinterpret_cast<const uint32_t*>(p), a, v);
    h = a * h + v;
    *o = f32_to_bf16(h);
    p += N1; o += E;
  }
}

extern "C" void kernel_launch(void* const* d_in, const int* in_sizes, int n_in,
                              void* d_out, int out_size, void* d_ws, size_t ws_size,
                              hipStream_t stream) {
  const float* x   = (const float*)d_in[0];
  const float* W_f = (const float*)d_in[1];
  const float* b_f = (const float*)d_in[2];
  const float* W_d = (const float*)d_in[3];
  const int Bb = 4, T = 4096, D = 1024, E = 1536;
  const int M = Bb * T;        // 16384
  const int N1 = 2 * E;        // 3072
  const int CH = 64, L = T / CH;

  char* w = (char*)d_ws;
  uint16_t* x_bf  = (uint16_t*)w; w += (size_t)M * D * 2;
  uint16_t* Wf_bf = (uint16_t*)w; w += (size_t)N1 * D * 2;
  uint16_t* Wd_bf = (uint16_t*)w; w += (size_t)D * E * 2;
  uint16_t* proj  = (uint16_t*)w; w += (size_t)M * N1 * 2;
  uint16_t* h_bf  = (uint16_t*)w; w += (size_t)M * E * 2;
  float* Ac     = (float*)w; w += (size_t)Bb * CH * E * 4;
  float* Vc     = (float*)w; w += (size_t)Bb * CH * E * 4;
  float* bias_p = (float*)w; w += (size_t)N1 * 4;

  cast_all<<<2048, 256, 0, stream>>>(x, x_bf, W_f, Wf_bf, b_f, bias_p, W_d, Wd_bf);

  // proj = x @ Wf_perm^T + bias_p (bf16, interleaved) + LDS-scan summaries
  gemm256<1, 1><<<(M / 256) * (N1 / 256), 512, 0, stream>>>(
      x_bf, Wf_bf, bias_p, proj, Ac, Vc, M, N1, D);

  scan_pass3<<<dim3(E / 256, CH, Bb), 256, 0, stream>>>(proj, Ac, Vc, h_bf, T, E, CH, L);

  // out = h @ W_down^T (fp32 out)
  gemm256<0, 0><<<(M / 256) * (D / 256), 512, 0, stream>>>(
      h_bf, Wd_bf, nullptr, d_out, nullptr, nullptr, M, D, E);
}